// Round 2
// baseline (7344.553 us; speedup 1.0000x reference)
//
#include <hip/hip_runtime.h>
#include <cstdint>
#include <cstddef>

// Problem constants (fixed by the reference)
static constexpr int NN = 100000;   // nodes
static constexpr int NE = 3200000;  // edges
static constexpr int NG = 256;      // graphs
static constexpr int NBK = (NN + 127) / 128;  // dst/src buckets of 128 nodes = 782
static constexpr int EPB = NE / 256;          // edges per hist/scatter block = 12500

__device__ __forceinline__ void atomAddF(float* p, float v) {
  unsafeAtomicAdd(p, v);  // native global_atomic_add_f32 on gfx950
}

// ---------------------------------------------------------------------------
// dtype hedge: reference says int64, harness doc says int32. Detect at runtime.
__global__ void k_detect(const int* __restrict__ ei, int* __restrict__ flag) {
  if (threadIdx.x == 0 && blockIdx.x == 0) {
    int nz = 0;
    for (int i = 0; i < 64; ++i) nz += (ei[2 * i + 1] != 0) ? 1 : 0;
    *flag = (nz == 0) ? 1 : 0;  // 1 => int64 layout
  }
}

__device__ __forceinline__ int ld_idx(const void* raw, int f, int i) {
  return f ? (int)((const long long*)raw)[i] : ((const int*)raw)[i];
}

// batch repack + graph counts (batch is sorted -> per-block run aggregation)
__global__ __launch_bounds__(256) void k_repack_batch(const void* __restrict__ raw,
                                                      const int* __restrict__ flag,
                                                      int* __restrict__ b32,
                                                      int* __restrict__ gcnt) {
  __shared__ int cnt[256];
  int t = threadIdx.x;
  cnt[t] = 0;
  int blk0 = blockIdx.x * 256;
  int f = *flag;
  int g0 = ld_idx(raw, f, blk0);  // block covers <=256 nodes -> graphs in [g0, g0+255]
  __syncthreads();
  int i = blk0 + t;
  if (i < NN) {
    int g = ld_idx(raw, f, i);
    b32[i] = g;
    atomicAdd(&cnt[g - g0], 1);
  }
  __syncthreads();
  if (cnt[t] > 0) atomicAdd(&gcnt[g0 + t], cnt[t]);
}

// ---------------------------------------------------------------------------
// Pass 1: per-block LDS histograms of src-buckets and dst-buckets.
__global__ __launch_bounds__(256) void k_hist(const void* __restrict__ raw,
                                              const int* __restrict__ flag,
                                              int* __restrict__ sCnt,
                                              int* __restrict__ dCnt) {
  __shared__ int hs[NBK], hd[NBK];
  int t = threadIdx.x;
  for (int i = t; i < NBK; i += 256) { hs[i] = 0; hd[i] = 0; }
  __syncthreads();
  int f = *flag;
  int e0 = blockIdx.x * EPB;
  for (int e = e0 + t; e < e0 + EPB; e += 256) {
    int s = ld_idx(raw, f, e);
    int d = ld_idx(raw, f, NE + e);
    atomicAdd(&hs[s >> 7], 1);
    atomicAdd(&hd[d >> 7], 1);
  }
  __syncthreads();
  for (int i = t; i < NBK; i += 256) {
    if (hs[i]) atomicAdd(&sCnt[i], hs[i]);
    if (hd[i]) atomicAdd(&dCnt[i], hd[i]);
  }
}

// Exclusive scan of both bucket-count arrays (782 <= 1024, one block).
__global__ __launch_bounds__(1024) void k_scan(const int* __restrict__ sCnt,
                                               const int* __restrict__ dCnt,
                                               int* __restrict__ sBase,
                                               int* __restrict__ dBase,
                                               int* __restrict__ sCur,
                                               int* __restrict__ dCur) {
  __shared__ int sh1[1024], sh2[1024];
  int t = threadIdx.x;
  int v1 = (t < NBK) ? sCnt[t] : 0;
  int v2 = (t < NBK) ? dCnt[t] : 0;
  sh1[t] = v1; sh2[t] = v2;
  __syncthreads();
  for (int off = 1; off < 1024; off <<= 1) {
    int a1 = (t >= off) ? sh1[t - off] : 0;
    int a2 = (t >= off) ? sh2[t - off] : 0;
    __syncthreads();
    sh1[t] += a1; sh2[t] += a2;
    __syncthreads();
  }
  if (t <= NBK) {
    int b1 = sh1[t] - v1, b2 = sh2[t] - v2;  // exclusive
    sBase[t] = b1; dBase[t] = b2;
    if (t < NBK) { sCur[t] = b1; dCur[t] = b2; }
  }
}

// Pass 2: chunk-reserve per (block,bucket), scatter src ids (by src bucket)
// and packed (src | dst_local<<17) records (by dst bucket).
__global__ __launch_bounds__(256) void k_scatter(const void* __restrict__ raw,
                                                 const int* __restrict__ flag,
                                                 int* __restrict__ sCur,
                                                 int* __restrict__ dCur,
                                                 int* __restrict__ srclist,
                                                 unsigned* __restrict__ elist) {
  __shared__ int hs[NBK], hd[NBK], cbS[NBK], cbD[NBK];
  int t = threadIdx.x;
  for (int i = t; i < NBK; i += 256) { hs[i] = 0; hd[i] = 0; }
  __syncthreads();
  int f = *flag;
  int e0 = blockIdx.x * EPB;
  for (int e = e0 + t; e < e0 + EPB; e += 256) {
    int s = ld_idx(raw, f, e);
    int d = ld_idx(raw, f, NE + e);
    atomicAdd(&hs[s >> 7], 1);
    atomicAdd(&hd[d >> 7], 1);
  }
  __syncthreads();
  for (int i = t; i < NBK; i += 256) {
    int c1 = hs[i];
    cbS[i] = c1 ? atomicAdd(&sCur[i], c1) : 0;
    int c2 = hd[i];
    cbD[i] = c2 ? atomicAdd(&dCur[i], c2) : 0;
  }
  __syncthreads();
  for (int i = t; i < NBK; i += 256) { hs[i] = 0; hd[i] = 0; }
  __syncthreads();
  for (int e = e0 + t; e < e0 + EPB; e += 256) {
    int s = ld_idx(raw, f, e);
    int d = ld_idx(raw, f, NE + e);
    int bs = s >> 7, bd = d >> 7;
    int ls = atomicAdd(&hs[bs], 1);
    int ld2 = atomicAdd(&hd[bd], 1);
    srclist[cbS[bs] + ls] = s;
    elist[cbD[bd] + ld2] = (unsigned)s | ((unsigned)(d & 127) << 17);
  }
}

// Out-degree per node from src-bucket-sorted list -> dinv.
__global__ __launch_bounds__(256) void k_deg(const int* __restrict__ sBase,
                                             const int* __restrict__ srclist,
                                             float* __restrict__ dinv) {
  __shared__ int cnt[128];
  int t = threadIdx.x;
  if (t < 128) cnt[t] = 0;
  __syncthreads();
  int b = blockIdx.x;
  int e0 = sBase[b], e1 = sBase[b + 1];
  for (int i = e0 + t; i < e1; i += 256) atomicAdd(&cnt[srclist[i] & 127], 1);
  __syncthreads();
  if (t < 128) {
    int node = b * 128 + t;
    if (node < NN) {
      int c = cnt[t];
      dinv[node] = (c > 0) ? rsqrtf((float)c) : 0.f;
    }
  }
}

// ---------------------------------------------------------------------------
// Propagation: one block per dst bucket (128 nodes x 64 dims LDS accumulator).
// out_plain  = -dinv  .* sum_{e->i} vin[src]
// out_scaled = -dinv^2 .* sum        (either pointer may be null)
__global__ __launch_bounds__(256) void k_prop(const int* __restrict__ dBase,
                                              const unsigned* __restrict__ elist,
                                              const float* __restrict__ vin,
                                              const float* __restrict__ dinv,
                                              float* __restrict__ o_plain,
                                              float* __restrict__ o_scaled) {
  __shared__ float acc[128 * 64];
  int t = threadIdx.x;
  for (int i = t; i < 8192; i += 256) acc[i] = 0.f;
  __syncthreads();
  int b = blockIdx.x;
  int e0 = dBase[b], e1 = dBase[b + 1];
  int lane = t & 63;
  for (int base_i = e0 + (t >> 6) * 64; base_i < e1; base_i += 256) {
    int n = e1 - base_i;
    if (n > 64) n = 64;
    unsigned ew = (lane < n) ? elist[base_i + lane] : 0u;
    int i = 0;
    for (; i + 8 <= n; i += 8) {
      float v[8];
      int dl[8];
#pragma unroll
      for (int u = 0; u < 8; ++u) {
        unsigned w2 = __shfl(ew, i + u);
        int s = (int)(w2 & 0x1FFFFu);
        dl[u] = (int)(w2 >> 17);
        v[u] = vin[s * 64 + lane];
      }
#pragma unroll
      for (int u = 0; u < 8; ++u) atomicAdd(&acc[dl[u] * 64 + lane], v[u]);
    }
    for (; i < n; ++i) {
      unsigned w2 = __shfl(ew, i);
      int s = (int)(w2 & 0x1FFFFu);
      atomicAdd(&acc[((int)(w2 >> 17)) * 64 + lane], vin[s * 64 + lane]);
    }
  }
  __syncthreads();
  int nb = b * 128;
  for (int i = t; i < 8192; i += 256) {
    int node = nb + (i >> 6);
    if (node < NN) {
      float dv = dinv[node];
      float p = -dv * acc[i];
      int d = i & 63;
      if (o_plain)  o_plain[node * 64 + d] = p;
      if (o_scaled) o_scaled[node * 64 + d] = dv * p;
    }
  }
}

// ---------------------------------------------------------------------------
// GEMM X: V0 = x@(W1[0]-W1[2]), U1s = dinv.*(x@W1[1]), U2s = dinv.*(x@W1[2]).
// Tile: 128 nodes x 64 dims, 256 threads, microtile 8 nodes x 4 dims.
__global__ __launch_bounds__(256) void k_gemm_x(const float* __restrict__ x,
                                                const float* __restrict__ W1,
                                                const float* __restrict__ dinv,
                                                float* __restrict__ V0,
                                                float* __restrict__ U1s,
                                                float* __restrict__ U2s) {
  __shared__ __align__(16) float Xs[16][132];
  __shared__ __align__(16) float WsA[16][64];  // W0 - W2
  __shared__ __align__(16) float WsB[16][64];  // W1
  __shared__ __align__(16) float WsC[16][64];  // W2
  const int t = threadIdx.x;
  const int d4 = (t & 15) * 4;
  const int ng = t >> 4;
  const int n0 = blockIdx.x * 128;
  float acc0[8][4], acc1[8][4], acc2[8][4];
#pragma unroll
  for (int j = 0; j < 8; ++j)
#pragma unroll
    for (int c = 0; c < 4; ++c) { acc0[j][c] = 0.f; acc1[j][c] = 0.f; acc2[j][c] = 0.f; }

  for (int kc = 0; kc < 128; kc += 16) {
#pragma unroll
    for (int u = 0; u < 2; ++u) {
      int lin = t * 2 + u;
      int i = lin >> 2, q = lin & 3;
      int row = n0 + i;
      float4 v = make_float4(0.f, 0.f, 0.f, 0.f);
      if (row < NN) v = *reinterpret_cast<const float4*>(x + (size_t)row * 128 + kc + q * 4);
      int k0 = q * 4;
      Xs[k0 + 0][i] = v.x; Xs[k0 + 1][i] = v.y; Xs[k0 + 2][i] = v.z; Xs[k0 + 3][i] = v.w;
    }
    {
      int kk = t >> 4, dq = (t & 15) * 4;
      float4 w0 = *reinterpret_cast<const float4*>(W1 + (size_t)(kc + kk) * 64 + dq);
      float4 w1 = *reinterpret_cast<const float4*>(W1 + (size_t)(8192 + (kc + kk) * 64) + dq);
      float4 w2 = *reinterpret_cast<const float4*>(W1 + (size_t)(16384 + (kc + kk) * 64) + dq);
      *reinterpret_cast<float4*>(&WsA[kk][dq]) =
          make_float4(w0.x - w2.x, w0.y - w2.y, w0.z - w2.z, w0.w - w2.w);
      *reinterpret_cast<float4*>(&WsB[kk][dq]) = w1;
      *reinterpret_cast<float4*>(&WsC[kk][dq]) = w2;
    }
    __syncthreads();
#pragma unroll
    for (int kk = 0; kk < 16; ++kk) {
      float4 xa = *reinterpret_cast<const float4*>(&Xs[kk][ng * 8]);
      float4 xb = *reinterpret_cast<const float4*>(&Xs[kk][ng * 8 + 4]);
      float4 wa = *reinterpret_cast<const float4*>(&WsA[kk][d4]);
      float4 wb = *reinterpret_cast<const float4*>(&WsB[kk][d4]);
      float4 wc = *reinterpret_cast<const float4*>(&WsC[kk][d4]);
      float xr[8] = {xa.x, xa.y, xa.z, xa.w, xb.x, xb.y, xb.z, xb.w};
      float war[4] = {wa.x, wa.y, wa.z, wa.w};
      float wbr[4] = {wb.x, wb.y, wb.z, wb.w};
      float wcr[4] = {wc.x, wc.y, wc.z, wc.w};
#pragma unroll
      for (int j = 0; j < 8; ++j)
#pragma unroll
        for (int c = 0; c < 4; ++c) {
          acc0[j][c] += xr[j] * war[c];
          acc1[j][c] += xr[j] * wbr[c];
          acc2[j][c] += xr[j] * wcr[c];
        }
    }
    __syncthreads();
  }
#pragma unroll
  for (int j = 0; j < 8; ++j) {
    int row = n0 + ng * 8 + j;
    if (row < NN) {
      float dv = dinv[row];
      *reinterpret_cast<float4*>(V0 + row * 64 + d4) =
          make_float4(acc0[j][0], acc0[j][1], acc0[j][2], acc0[j][3]);
      *reinterpret_cast<float4*>(U1s + row * 64 + d4) =
          make_float4(dv * acc1[j][0], dv * acc1[j][1], dv * acc1[j][2], dv * acc1[j][3]);
      *reinterpret_cast<float4*>(U2s + row * 64 + d4) =
          make_float4(dv * acc2[j][0], dv * acc2[j][1], dv * acc2[j][2], dv * acc2[j][3]);
    }
  }
}

// h1 = relu(V0 + P + 2R + b1); h1s = dinv .* h1  (elementwise)
__global__ __launch_bounds__(256) void k_h1(const float* __restrict__ V0,
                                            const float* __restrict__ P,
                                            const float* __restrict__ R,
                                            const float* __restrict__ b1v,
                                            const float* __restrict__ dinv,
                                            float* __restrict__ h1,
                                            float* __restrict__ h1s) {
  int idx = blockIdx.x * 256 + threadIdx.x;
  if (idx >= NN * 16) return;
  int row = idx >> 4, c = (idx & 15) * 4;
  float dv = dinv[row];
  float4 v0 = *reinterpret_cast<const float4*>(V0 + row * 64 + c);
  float4 p = *reinterpret_cast<const float4*>(P + row * 64 + c);
  float4 r = *reinterpret_cast<const float4*>(R + row * 64 + c);
  float4 b = *reinterpret_cast<const float4*>(b1v + c);
  float4 h;
  h.x = fmaxf(v0.x + p.x + 2.f * r.x + b.x, 0.f);
  h.y = fmaxf(v0.y + p.y + 2.f * r.y + b.y, 0.f);
  h.z = fmaxf(v0.z + p.z + 2.f * r.z + b.z, 0.f);
  h.w = fmaxf(v0.w + p.w + 2.f * r.w + b.w, 0.f);
  *reinterpret_cast<float4*>(h1 + row * 64 + c) = h;
  *reinterpret_cast<float4*>(h1s + row * 64 + c) =
      make_float4(dv * h.x, dv * h.y, dv * h.z, dv * h.w);
}

// GEMM C: h2 = relu(h1@(W2[0]-W2[2]) + T1@W2[1] + T2@(2*W2[2]) + b2),
// fused segmented mean-pool numerator (batch sorted) into pooled[] atomics.
__global__ __launch_bounds__(256) void k_gemm_h2_pool(const float* __restrict__ h1,
                                                      const float* __restrict__ T1,
                                                      const float* __restrict__ T2,
                                                      const float* __restrict__ W2,
                                                      const float* __restrict__ b2v,
                                                      const int* __restrict__ b32,
                                                      float* __restrict__ pooled) {
  __shared__ __align__(16) float smem[9408];  // 3*16*132 + 3*16*64
  __shared__ int gb[128];
  float (*Xh)[132]  = reinterpret_cast<float (*)[132]>(smem);
  float (*Xt1)[132] = reinterpret_cast<float (*)[132]>(smem + 2112);
  float (*Xt2)[132] = reinterpret_cast<float (*)[132]>(smem + 4224);
  float (*Wa)[64]   = reinterpret_cast<float (*)[64]>(smem + 6336);
  float (*Wb)[64]   = reinterpret_cast<float (*)[64]>(smem + 7360);
  float (*Wc)[64]   = reinterpret_cast<float (*)[64]>(smem + 8384);
  float (*ht)[68]   = reinterpret_cast<float (*)[68]>(smem);  // aliases Xs after K-loop

  const int t = threadIdx.x;
  const int d4 = (t & 15) * 4;
  const int ng = t >> 4;
  const int n0 = blockIdx.x * 128;
  if (t < 128) gb[t] = (n0 + t < NN) ? b32[n0 + t] : -1;

  float acc[8][4];
#pragma unroll
  for (int j = 0; j < 8; ++j)
#pragma unroll
    for (int c = 0; c < 4; ++c) acc[j][c] = 0.f;

  for (int kc = 0; kc < 64; kc += 16) {
#pragma unroll
    for (int u = 0; u < 2; ++u) {
      int lin = t * 2 + u;
      int i = lin >> 2, q = lin & 3;
      int row = n0 + i;
      float4 vh = make_float4(0.f, 0.f, 0.f, 0.f), v1 = vh, v2 = vh;
      if (row < NN) {
        vh = *reinterpret_cast<const float4*>(h1 + (size_t)row * 64 + kc + q * 4);
        v1 = *reinterpret_cast<const float4*>(T1 + (size_t)row * 64 + kc + q * 4);
        v2 = *reinterpret_cast<const float4*>(T2 + (size_t)row * 64 + kc + q * 4);
      }
      int k0 = q * 4;
      Xh[k0 + 0][i] = vh.x; Xh[k0 + 1][i] = vh.y; Xh[k0 + 2][i] = vh.z; Xh[k0 + 3][i] = vh.w;
      Xt1[k0 + 0][i] = v1.x; Xt1[k0 + 1][i] = v1.y; Xt1[k0 + 2][i] = v1.z; Xt1[k0 + 3][i] = v1.w;
      Xt2[k0 + 0][i] = v2.x; Xt2[k0 + 1][i] = v2.y; Xt2[k0 + 2][i] = v2.z; Xt2[k0 + 3][i] = v2.w;
    }
    {
      int kk = t >> 4, dq = (t & 15) * 4;
      float4 w0 = *reinterpret_cast<const float4*>(W2 + (size_t)(kc + kk) * 64 + dq);
      float4 w1 = *reinterpret_cast<const float4*>(W2 + 4096 + (size_t)(kc + kk) * 64 + dq);
      float4 w2 = *reinterpret_cast<const float4*>(W2 + 8192 + (size_t)(kc + kk) * 64 + dq);
      float4 wa = make_float4(w0.x - w2.x, w0.y - w2.y, w0.z - w2.z, w0.w - w2.w);
      float4 wc = make_float4(2.f * w2.x, 2.f * w2.y, 2.f * w2.z, 2.f * w2.w);
      *reinterpret_cast<float4*>(&Wa[kk][dq]) = wa;
      *reinterpret_cast<float4*>(&Wb[kk][dq]) = w1;
      *reinterpret_cast<float4*>(&Wc[kk][dq]) = wc;
    }
    __syncthreads();
#pragma unroll
    for (int kk = 0; kk < 16; ++kk) {
      float4 ha = *reinterpret_cast<const float4*>(&Xh[kk][ng * 8]);
      float4 hb = *reinterpret_cast<const float4*>(&Xh[kk][ng * 8 + 4]);
      float4 p1a = *reinterpret_cast<const float4*>(&Xt1[kk][ng * 8]);
      float4 p1b = *reinterpret_cast<const float4*>(&Xt1[kk][ng * 8 + 4]);
      float4 p2a = *reinterpret_cast<const float4*>(&Xt2[kk][ng * 8]);
      float4 p2b = *reinterpret_cast<const float4*>(&Xt2[kk][ng * 8 + 4]);
      float4 wa = *reinterpret_cast<const float4*>(&Wa[kk][d4]);
      float4 wb = *reinterpret_cast<const float4*>(&Wb[kk][d4]);
      float4 wc = *reinterpret_cast<const float4*>(&Wc[kk][d4]);
      float hr[8] = {ha.x, ha.y, ha.z, ha.w, hb.x, hb.y, hb.z, hb.w};
      float r1[8] = {p1a.x, p1a.y, p1a.z, p1a.w, p1b.x, p1b.y, p1b.z, p1b.w};
      float r2[8] = {p2a.x, p2a.y, p2a.z, p2a.w, p2b.x, p2b.y, p2b.z, p2b.w};
      float war[4] = {wa.x, wa.y, wa.z, wa.w};
      float wbr[4] = {wb.x, wb.y, wb.z, wb.w};
      float wcr[4] = {wc.x, wc.y, wc.z, wc.w};
#pragma unroll
      for (int j = 0; j < 8; ++j)
#pragma unroll
        for (int c = 0; c < 4; ++c)
          acc[j][c] += hr[j] * war[c] + r1[j] * wbr[c] + r2[j] * wcr[c];
    }
    __syncthreads();
  }
  // epilogue: relu + bias into LDS tile (aliased over Xs, safe after barrier)
  float4 bv = *reinterpret_cast<const float4*>(b2v + d4);
#pragma unroll
  for (int j = 0; j < 8; ++j) {
    int r = ng * 8 + j;
    float4 o;
    o.x = fmaxf(acc[j][0] + bv.x, 0.f);
    o.y = fmaxf(acc[j][1] + bv.y, 0.f);
    o.z = fmaxf(acc[j][2] + bv.z, 0.f);
    o.w = fmaxf(acc[j][3] + bv.w, 0.f);
    *reinterpret_cast<float4*>(&ht[r][d4]) = o;
  }
  __syncthreads();
  // segmented pool: batch sorted -> run-length reduce 32 rows per quarter-block
  int rg = t >> 6;
  int d = t & 63;
  int base = rg * 32;
  int cur = -2;
  float s = 0.f;
  for (int i2 = 0; i2 < 32; ++i2) {
    int g = gb[base + i2];  // wave-uniform
    if (g != cur) {
      if (cur >= 0) atomAddF(&pooled[cur * 64 + d], s);
      s = 0.f;
      cur = g;
    }
    if (g >= 0) s += ht[base + i2][d];
  }
  if (cur >= 0) atomAddF(&pooled[cur * 64 + d], s);
}

// Final: out[g] = dot(pooled[g]/max(cnt,1), Wfc) + bfc
__global__ void k_out(const float* __restrict__ pooled, const int* __restrict__ gcnt,
                      const float* __restrict__ Wfc, const float* __restrict__ bfc,
                      float* __restrict__ out) {
  int g = blockIdx.x, t = threadIdx.x;  // 64 threads
  float v = pooled[g * 64 + t] * Wfc[t];
  int c = gcnt[g];
  v /= (float)(c > 0 ? c : 1);
  for (int off = 32; off > 0; off >>= 1) v += __shfl_down(v, off, 64);
  if (t == 0) out[g] = v + bfc[0];
}

// ---------------------------------------------------------------------------
extern "C" void kernel_launch(void* const* d_in, const int* in_sizes, int n_in,
                              void* d_out, int out_size, void* d_ws, size_t ws_size,
                              hipStream_t stream) {
  const float* x   = (const float*)d_in[0];
  const void*  ei  = d_in[1];
  const void*  bat = d_in[2];
  const float* W1  = (const float*)d_in[3];
  const float* b1v = (const float*)d_in[4];
  const float* W2  = (const float*)d_in[5];
  const float* b2v = (const float*)d_in[6];
  const float* Wfc = (const float*)d_in[7];
  const float* bfc = (const float*)d_in[8];
  float* out = (float*)d_out;

  char* w = (char*)d_ws;
  size_t o = 0;
  auto take = [&](size_t bytes) -> void* {
    void* p = w + o;
    o = (o + bytes + 255) & ~(size_t)255;
    return p;
  };
  int*      flag   = (int*)take(256);
  // ---- zero region start
  int*      gcnt   = (int*)take((size_t)NG * 4);
  float*    pooled = (float*)take((size_t)NG * 64 * 4);
  int*      sCnt   = (int*)take((size_t)(NBK + 2) * 4);
  int*      dCnt   = (int*)take((size_t)(NBK + 2) * 4);
  // ---- zero region end
  char*     zend   = w + o;
  int*      sBase  = (int*)take((size_t)(NBK + 2) * 4);
  int*      dBase  = (int*)take((size_t)(NBK + 2) * 4);
  int*      sCur   = (int*)take((size_t)(NBK + 2) * 4);
  int*      dCur   = (int*)take((size_t)(NBK + 2) * 4);
  int*      b32    = (int*)take((size_t)NN * 4);
  float*    dinv   = (float*)take((size_t)NN * 4);
  int*      srclist= (int*)take((size_t)NE * 4);
  unsigned* elist  = (unsigned*)take((size_t)NE * 4);
  float*    f0     = (float*)take((size_t)NN * 64 * 4);
  float*    f1     = (float*)take((size_t)NN * 64 * 4);
  float*    f2     = (float*)take((size_t)NN * 64 * 4);
  float*    f3     = (float*)take((size_t)NN * 64 * 4);
  float*    f4     = (float*)take((size_t)NN * 64 * 4);
  (void)in_sizes; (void)n_in; (void)out_size; (void)ws_size;

  hipMemsetAsync(gcnt, 0, (size_t)(zend - (char*)gcnt), stream);

  k_detect<<<1, 64, 0, stream>>>((const int*)ei, flag);
  k_repack_batch<<<(NN + 255) / 256, 256, 0, stream>>>(bat, flag, b32, gcnt);
  k_hist<<<256, 256, 0, stream>>>(ei, flag, sCnt, dCnt);
  k_scan<<<1, 1024, 0, stream>>>(sCnt, dCnt, sBase, dBase, sCur, dCur);
  k_scatter<<<256, 256, 0, stream>>>(ei, flag, sCur, dCur, srclist, elist);
  k_deg<<<NBK, 256, 0, stream>>>(sBase, srclist, dinv);

  const int gemm_grid = (NN + 127) / 128;  // 782

  // Layer 1: V0 = x(W0-W2) -> f4, U1s -> f0, U2s -> f1
  k_gemm_x<<<gemm_grid, 256, 0, stream>>>(x, W1, dinv, f4, f0, f1);
  k_prop<<<NBK, 256, 0, stream>>>(dBase, elist, f0, dinv, f2, nullptr);   // P  -> f2
  k_prop<<<NBK, 256, 0, stream>>>(dBase, elist, f1, dinv, nullptr, f3);   // Qs -> f3
  k_prop<<<NBK, 256, 0, stream>>>(dBase, elist, f3, dinv, f1, nullptr);   // R  -> f1
  k_h1<<<(NN * 16 + 255) / 256, 256, 0, stream>>>(f4, f2, f1, b1v, dinv, f3, f0); // h1->f3, h1s->f0
  // Layer 2:
  k_prop<<<NBK, 256, 0, stream>>>(dBase, elist, f0, dinv, f2, f1);        // T1 -> f2, T1s -> f1
  k_prop<<<NBK, 256, 0, stream>>>(dBase, elist, f1, dinv, f4, nullptr);   // T2 -> f4
  k_gemm_h2_pool<<<gemm_grid, 256, 0, stream>>>(f3, f2, f4, W2, b2v, b32, pooled);
  k_out<<<NG, 64, 0, stream>>>(pooled, gcnt, Wfc, bfc, out);
}

// Round 3
// 1036.862 us; speedup vs baseline: 7.0834x; 7.0834x over previous
//
#include <hip/hip_runtime.h>
#include <cstdint>
#include <cstddef>

// Problem constants (fixed by the reference)
static constexpr int NN = 100000;   // nodes
static constexpr int NE = 3200000;  // edges
static constexpr int NG = 256;      // graphs
static constexpr int NBK = (NN + 127) / 128;  // dst/src buckets of 128 nodes = 782
static constexpr int EPB = NE / 256;          // edges per hist/scatter block = 12500

__device__ __forceinline__ void atomAddF(float* p, float v) {
  unsafeAtomicAdd(p, v);  // native global_atomic_add_f32 on gfx950
}

// ---------------------------------------------------------------------------
// dtype hedge: reference says int64, harness doc says int32. Detect at runtime.
__global__ void k_detect(const int* __restrict__ ei, int* __restrict__ flag) {
  if (threadIdx.x == 0 && blockIdx.x == 0) {
    int nz = 0;
    for (int i = 0; i < 64; ++i) nz += (ei[2 * i + 1] != 0) ? 1 : 0;
    *flag = (nz == 0) ? 1 : 0;  // 1 => int64 layout
  }
}

__device__ __forceinline__ int ld_idx(const void* raw, int f, int i) {
  return f ? (int)((const long long*)raw)[i] : ((const int*)raw)[i];
}

// batch repack + graph counts (batch is sorted -> per-block run aggregation)
__global__ __launch_bounds__(256) void k_repack_batch(const void* __restrict__ raw,
                                                      const int* __restrict__ flag,
                                                      int* __restrict__ b32,
                                                      int* __restrict__ gcnt) {
  __shared__ int cnt[256];
  int t = threadIdx.x;
  cnt[t] = 0;
  int blk0 = blockIdx.x * 256;
  int f = *flag;
  int g0 = ld_idx(raw, f, blk0);  // batch sorted, ids < 256 -> g-g0 in [0,255]
  __syncthreads();
  int i = blk0 + t;
  if (i < NN) {
    int g = ld_idx(raw, f, i);
    b32[i] = g;
    atomicAdd(&cnt[g - g0], 1);
  }
  __syncthreads();
  if (cnt[t] > 0) atomicAdd(&gcnt[g0 + t], cnt[t]);
}

// ---------------------------------------------------------------------------
// Pass 1: per-block LDS histograms of src-buckets and dst-buckets.
__global__ __launch_bounds__(256) void k_hist(const void* __restrict__ raw,
                                              const int* __restrict__ flag,
                                              int* __restrict__ sCnt,
                                              int* __restrict__ dCnt) {
  __shared__ int hs[NBK], hd[NBK];
  int t = threadIdx.x;
  for (int i = t; i < NBK; i += 256) { hs[i] = 0; hd[i] = 0; }
  __syncthreads();
  int f = *flag;
  int e0 = blockIdx.x * EPB;
  for (int e = e0 + t; e < e0 + EPB; e += 256) {
    int s = ld_idx(raw, f, e);
    int d = ld_idx(raw, f, NE + e);
    atomicAdd(&hs[s >> 7], 1);
    atomicAdd(&hd[d >> 7], 1);
  }
  __syncthreads();
  for (int i = t; i < NBK; i += 256) {
    if (hs[i]) atomicAdd(&sCnt[i], hs[i]);
    if (hd[i]) atomicAdd(&dCnt[i], hd[i]);
  }
}

// Exclusive scan of both bucket-count arrays (782 <= 1024, one block).
__global__ __launch_bounds__(1024) void k_scan(const int* __restrict__ sCnt,
                                               const int* __restrict__ dCnt,
                                               int* __restrict__ sBase,
                                               int* __restrict__ dBase,
                                               int* __restrict__ sCur,
                                               int* __restrict__ dCur) {
  __shared__ int sh1[1024], sh2[1024];
  int t = threadIdx.x;
  int v1 = (t < NBK) ? sCnt[t] : 0;
  int v2 = (t < NBK) ? dCnt[t] : 0;
  sh1[t] = v1; sh2[t] = v2;
  __syncthreads();
  for (int off = 1; off < 1024; off <<= 1) {
    int a1 = (t >= off) ? sh1[t - off] : 0;
    int a2 = (t >= off) ? sh2[t - off] : 0;
    __syncthreads();
    sh1[t] += a1; sh2[t] += a2;
    __syncthreads();
  }
  if (t <= NBK) {
    int b1 = sh1[t] - v1, b2 = sh2[t] - v2;  // exclusive
    sBase[t] = b1; dBase[t] = b2;
    if (t < NBK) { sCur[t] = b1; dCur[t] = b2; }
  }
}

// Pass 2: chunk-reserve per (block,bucket), scatter src ids (by src bucket)
// and packed (src | dst_local<<17) records (by dst bucket).
__global__ __launch_bounds__(256) void k_scatter(const void* __restrict__ raw,
                                                 const int* __restrict__ flag,
                                                 int* __restrict__ sCur,
                                                 int* __restrict__ dCur,
                                                 int* __restrict__ srclist,
                                                 unsigned* __restrict__ elist) {
  __shared__ int hs[NBK], hd[NBK], cbS[NBK], cbD[NBK];
  int t = threadIdx.x;
  for (int i = t; i < NBK; i += 256) { hs[i] = 0; hd[i] = 0; }
  __syncthreads();
  int f = *flag;
  int e0 = blockIdx.x * EPB;
  for (int e = e0 + t; e < e0 + EPB; e += 256) {
    int s = ld_idx(raw, f, e);
    int d = ld_idx(raw, f, NE + e);
    atomicAdd(&hs[s >> 7], 1);
    atomicAdd(&hd[d >> 7], 1);
  }
  __syncthreads();
  for (int i = t; i < NBK; i += 256) {
    int c1 = hs[i];
    cbS[i] = c1 ? atomicAdd(&sCur[i], c1) : 0;
    int c2 = hd[i];
    cbD[i] = c2 ? atomicAdd(&dCur[i], c2) : 0;
  }
  __syncthreads();
  for (int i = t; i < NBK; i += 256) { hs[i] = 0; hd[i] = 0; }
  __syncthreads();
  for (int e = e0 + t; e < e0 + EPB; e += 256) {
    int s = ld_idx(raw, f, e);
    int d = ld_idx(raw, f, NE + e);
    int bs = s >> 7, bd = d >> 7;
    int ls = atomicAdd(&hs[bs], 1);
    int ld2 = atomicAdd(&hd[bd], 1);
    srclist[cbS[bs] + ls] = s;
    elist[cbD[bd] + ld2] = (unsigned)s | ((unsigned)(d & 127) << 17);
  }
}

// Out-degree per node from src-bucket-sorted list -> dinv.
__global__ __launch_bounds__(256) void k_deg(const int* __restrict__ sBase,
                                             const int* __restrict__ srclist,
                                             float* __restrict__ dinv) {
  __shared__ int cnt[128];
  int t = threadIdx.x;
  if (t < 128) cnt[t] = 0;
  __syncthreads();
  int b = blockIdx.x;
  int e0 = sBase[b], e1 = sBase[b + 1];
  for (int i = e0 + t; i < e1; i += 256) atomicAdd(&cnt[srclist[i] & 127], 1);
  __syncthreads();
  if (t < 128) {
    int node = b * 128 + t;
    if (node < NN) {
      int c = cnt[t];
      dinv[node] = (c > 0) ? rsqrtf((float)c) : 0.f;
    }
  }
}

// Per-bucket counting sort: dst-bucketed elist -> true CSR (rowptr + adj).
__global__ __launch_bounds__(256) void k_csr(const int* __restrict__ dBase,
                                             const unsigned* __restrict__ elist,
                                             int* __restrict__ rowptr,
                                             int* __restrict__ adj) {
  __shared__ int cnt[128], sc[128], off[128], fill[128];
  int t = threadIdx.x;
  if (t < 128) { cnt[t] = 0; fill[t] = 0; }
  __syncthreads();
  int b = blockIdx.x;
  int e0 = dBase[b], e1 = dBase[b + 1];
  for (int i = e0 + t; i < e1; i += 256) atomicAdd(&cnt[elist[i] >> 17], 1);
  __syncthreads();
  if (t < 128) sc[t] = cnt[t];
  __syncthreads();
  for (int o = 1; o < 128; o <<= 1) {
    int a = (t < 128 && t >= o) ? sc[t - o] : 0;
    __syncthreads();
    if (t < 128) sc[t] += a;
    __syncthreads();
  }
  if (t < 128) {
    off[t] = sc[t] - cnt[t];  // exclusive
    int node = b * 128 + t;
    if (node < NN) rowptr[node] = e0 + off[t];
  }
  if (b == NBK - 1 && t == 0) rowptr[NN] = e1;
  __syncthreads();
  for (int i = e0 + t; i < e1; i += 256) {
    unsigned w2 = elist[i];
    int l = (int)(w2 >> 17);
    int pos = atomicAdd(&fill[l], 1);
    adj[e0 + off[l] + pos] = (int)(w2 & 0x1FFFFu);
  }
}

// ---------------------------------------------------------------------------
// Propagation (single input): wave per node, lane = dim, register accumulate.
// o_p = -dinv .* sum_{e->i} vin[src];  o_s = dinv .* o_p  (either may be null)
__global__ __launch_bounds__(256) void k_prop1(const int* __restrict__ rp,
                                               const int* __restrict__ adj,
                                               const float* __restrict__ vin,
                                               const float* __restrict__ dinv,
                                               float* __restrict__ o_p,
                                               float* __restrict__ o_s) {
  int node = blockIdx.x * 4 + (threadIdx.x >> 6);
  int d = threadIdx.x & 63;
  if (node >= NN) return;
  int p0 = rp[node], p1 = rp[node + 1];
  float a0 = 0.f, a1 = 0.f, a2 = 0.f, a3 = 0.f;
  int p = p0;
  int pA = (p0 + 3) & ~3;
  if (pA > p1) pA = p1;
  for (; p < pA; ++p) a0 += vin[(size_t)adj[p] * 64 + d];
  for (; p + 4 <= p1; p += 4) {
    int4 e = *reinterpret_cast<const int4*>(adj + p);  // uniform 16B load
    a0 += vin[(size_t)e.x * 64 + d];
    a1 += vin[(size_t)e.y * 64 + d];
    a2 += vin[(size_t)e.z * 64 + d];
    a3 += vin[(size_t)e.w * 64 + d];
  }
  for (; p < p1; ++p) a1 += vin[(size_t)adj[p] * 64 + d];
  float s = (a0 + a1) + (a2 + a3);
  float dv = dinv[node];
  float pl = -dv * s;
  if (o_p) o_p[(size_t)node * 64 + d] = pl;
  if (o_s) o_s[(size_t)node * 64 + d] = dv * pl;
}

// Propagation (two inputs, shared adjacency): A -> plain out, B -> scaled out.
__global__ __launch_bounds__(256) void k_prop2(const int* __restrict__ rp,
                                               const int* __restrict__ adj,
                                               const float* __restrict__ vinA,
                                               const float* __restrict__ vinB,
                                               const float* __restrict__ dinv,
                                               float* __restrict__ oA_p,
                                               float* __restrict__ oB_s) {
  int node = blockIdx.x * 4 + (threadIdx.x >> 6);
  int d = threadIdx.x & 63;
  if (node >= NN) return;
  int p0 = rp[node], p1 = rp[node + 1];
  float a0 = 0.f, a1 = 0.f, a2 = 0.f, a3 = 0.f;
  float b0 = 0.f, b1 = 0.f, b2 = 0.f, b3 = 0.f;
  int p = p0;
  int pA = (p0 + 3) & ~3;
  if (pA > p1) pA = p1;
  for (; p < pA; ++p) {
    size_t r = (size_t)adj[p] * 64 + d;
    a0 += vinA[r]; b0 += vinB[r];
  }
  for (; p + 4 <= p1; p += 4) {
    int4 e = *reinterpret_cast<const int4*>(adj + p);
    size_t r0 = (size_t)e.x * 64 + d, r1 = (size_t)e.y * 64 + d;
    size_t r2 = (size_t)e.z * 64 + d, r3 = (size_t)e.w * 64 + d;
    a0 += vinA[r0]; a1 += vinA[r1]; a2 += vinA[r2]; a3 += vinA[r3];
    b0 += vinB[r0]; b1 += vinB[r1]; b2 += vinB[r2]; b3 += vinB[r3];
  }
  for (; p < p1; ++p) {
    size_t r = (size_t)adj[p] * 64 + d;
    a1 += vinA[r]; b1 += vinB[r];
  }
  float sa = (a0 + a1) + (a2 + a3);
  float sb = (b0 + b1) + (b2 + b3);
  float dv = dinv[node];
  oA_p[(size_t)node * 64 + d] = -dv * sa;
  oB_s[(size_t)node * 64 + d] = -dv * dv * sb;
}

// ---------------------------------------------------------------------------
// GEMM X: V0 = x@(W1[0]-W1[2]), U1s = dinv.*(x@W1[1]), U2s = dinv.*(x@W1[2]).
__global__ __launch_bounds__(256) void k_gemm_x(const float* __restrict__ x,
                                                const float* __restrict__ W1,
                                                const float* __restrict__ dinv,
                                                float* __restrict__ V0,
                                                float* __restrict__ U1s,
                                                float* __restrict__ U2s) {
  __shared__ __align__(16) float Xs[16][132];
  __shared__ __align__(16) float WsA[16][64];  // W0 - W2
  __shared__ __align__(16) float WsB[16][64];  // W1
  __shared__ __align__(16) float WsC[16][64];  // W2
  const int t = threadIdx.x;
  const int d4 = (t & 15) * 4;
  const int ng = t >> 4;
  const int n0 = blockIdx.x * 128;
  float acc0[8][4], acc1[8][4], acc2[8][4];
#pragma unroll
  for (int j = 0; j < 8; ++j)
#pragma unroll
    for (int c = 0; c < 4; ++c) { acc0[j][c] = 0.f; acc1[j][c] = 0.f; acc2[j][c] = 0.f; }

  for (int kc = 0; kc < 128; kc += 16) {
#pragma unroll
    for (int u = 0; u < 2; ++u) {
      int lin = t * 2 + u;
      int i = lin >> 2, q = lin & 3;
      int row = n0 + i;
      float4 v = make_float4(0.f, 0.f, 0.f, 0.f);
      if (row < NN) v = *reinterpret_cast<const float4*>(x + (size_t)row * 128 + kc + q * 4);
      int k0 = q * 4;
      Xs[k0 + 0][i] = v.x; Xs[k0 + 1][i] = v.y; Xs[k0 + 2][i] = v.z; Xs[k0 + 3][i] = v.w;
    }
    {
      int kk = t >> 4, dq = (t & 15) * 4;
      float4 w0 = *reinterpret_cast<const float4*>(W1 + (size_t)(kc + kk) * 64 + dq);
      float4 w1 = *reinterpret_cast<const float4*>(W1 + (size_t)(8192 + (kc + kk) * 64) + dq);
      float4 w2 = *reinterpret_cast<const float4*>(W1 + (size_t)(16384 + (kc + kk) * 64) + dq);
      *reinterpret_cast<float4*>(&WsA[kk][dq]) =
          make_float4(w0.x - w2.x, w0.y - w2.y, w0.z - w2.z, w0.w - w2.w);
      *reinterpret_cast<float4*>(&WsB[kk][dq]) = w1;
      *reinterpret_cast<float4*>(&WsC[kk][dq]) = w2;
    }
    __syncthreads();
#pragma unroll
    for (int kk = 0; kk < 16; ++kk) {
      float4 xa = *reinterpret_cast<const float4*>(&Xs[kk][ng * 8]);
      float4 xb = *reinterpret_cast<const float4*>(&Xs[kk][ng * 8 + 4]);
      float4 wa = *reinterpret_cast<const float4*>(&WsA[kk][d4]);
      float4 wb = *reinterpret_cast<const float4*>(&WsB[kk][d4]);
      float4 wc = *reinterpret_cast<const float4*>(&WsC[kk][d4]);
      float xr[8] = {xa.x, xa.y, xa.z, xa.w, xb.x, xb.y, xb.z, xb.w};
      float war[4] = {wa.x, wa.y, wa.z, wa.w};
      float wbr[4] = {wb.x, wb.y, wb.z, wb.w};
      float wcr[4] = {wc.x, wc.y, wc.z, wc.w};
#pragma unroll
      for (int j = 0; j < 8; ++j)
#pragma unroll
        for (int c = 0; c < 4; ++c) {
          acc0[j][c] += xr[j] * war[c];
          acc1[j][c] += xr[j] * wbr[c];
          acc2[j][c] += xr[j] * wcr[c];
        }
    }
    __syncthreads();
  }
#pragma unroll
  for (int j = 0; j < 8; ++j) {
    int row = n0 + ng * 8 + j;
    if (row < NN) {
      float dv = dinv[row];
      *reinterpret_cast<float4*>(V0 + row * 64 + d4) =
          make_float4(acc0[j][0], acc0[j][1], acc0[j][2], acc0[j][3]);
      *reinterpret_cast<float4*>(U1s + row * 64 + d4) =
          make_float4(dv * acc1[j][0], dv * acc1[j][1], dv * acc1[j][2], dv * acc1[j][3]);
      *reinterpret_cast<float4*>(U2s + row * 64 + d4) =
          make_float4(dv * acc2[j][0], dv * acc2[j][1], dv * acc2[j][2], dv * acc2[j][3]);
    }
  }
}

// h1 = relu(V0 + P + 2R + b1); h1s = dinv .* h1  (elementwise)
__global__ __launch_bounds__(256) void k_h1(const float* __restrict__ V0,
                                            const float* __restrict__ P,
                                            const float* __restrict__ R,
                                            const float* __restrict__ b1v,
                                            const float* __restrict__ dinv,
                                            float* __restrict__ h1,
                                            float* __restrict__ h1s) {
  int idx = blockIdx.x * 256 + threadIdx.x;
  if (idx >= NN * 16) return;
  int row = idx >> 4, c = (idx & 15) * 4;
  float dv = dinv[row];
  float4 v0 = *reinterpret_cast<const float4*>(V0 + row * 64 + c);
  float4 p = *reinterpret_cast<const float4*>(P + row * 64 + c);
  float4 r = *reinterpret_cast<const float4*>(R + row * 64 + c);
  float4 b = *reinterpret_cast<const float4*>(b1v + c);
  float4 h;
  h.x = fmaxf(v0.x + p.x + 2.f * r.x + b.x, 0.f);
  h.y = fmaxf(v0.y + p.y + 2.f * r.y + b.y, 0.f);
  h.z = fmaxf(v0.z + p.z + 2.f * r.z + b.z, 0.f);
  h.w = fmaxf(v0.w + p.w + 2.f * r.w + b.w, 0.f);
  *reinterpret_cast<float4*>(h1 + row * 64 + c) = h;
  *reinterpret_cast<float4*>(h1s + row * 64 + c) =
      make_float4(dv * h.x, dv * h.y, dv * h.z, dv * h.w);
}

// GEMM C: h2 = relu(h1@(W2[0]-W2[2]) + T1@W2[1] + T2@(2*W2[2]) + b2),
// fused segmented mean-pool numerator (batch sorted) into pooled[] atomics.
__global__ __launch_bounds__(256) void k_gemm_h2_pool(const float* __restrict__ h1,
                                                      const float* __restrict__ T1,
                                                      const float* __restrict__ T2,
                                                      const float* __restrict__ W2,
                                                      const float* __restrict__ b2v,
                                                      const int* __restrict__ b32,
                                                      float* __restrict__ pooled) {
  __shared__ __align__(16) float smem[9408];  // 3*16*132 + 3*16*64
  __shared__ int gb[128];
  float (*Xh)[132]  = reinterpret_cast<float (*)[132]>(smem);
  float (*Xt1)[132] = reinterpret_cast<float (*)[132]>(smem + 2112);
  float (*Xt2)[132] = reinterpret_cast<float (*)[132]>(smem + 4224);
  float (*Wa)[64]   = reinterpret_cast<float (*)[64]>(smem + 6336);
  float (*Wb)[64]   = reinterpret_cast<float (*)[64]>(smem + 7360);
  float (*Wc)[64]   = reinterpret_cast<float (*)[64]>(smem + 8384);
  float (*ht)[68]   = reinterpret_cast<float (*)[68]>(smem);  // aliases Xs after K-loop

  const int t = threadIdx.x;
  const int d4 = (t & 15) * 4;
  const int ng = t >> 4;
  const int n0 = blockIdx.x * 128;
  if (t < 128) gb[t] = (n0 + t < NN) ? b32[n0 + t] : -1;

  float acc[8][4];
#pragma unroll
  for (int j = 0; j < 8; ++j)
#pragma unroll
    for (int c = 0; c < 4; ++c) acc[j][c] = 0.f;

  for (int kc = 0; kc < 64; kc += 16) {
#pragma unroll
    for (int u = 0; u < 2; ++u) {
      int lin = t * 2 + u;
      int i = lin >> 2, q = lin & 3;
      int row = n0 + i;
      float4 vh = make_float4(0.f, 0.f, 0.f, 0.f), v1 = vh, v2 = vh;
      if (row < NN) {
        vh = *reinterpret_cast<const float4*>(h1 + (size_t)row * 64 + kc + q * 4);
        v1 = *reinterpret_cast<const float4*>(T1 + (size_t)row * 64 + kc + q * 4);
        v2 = *reinterpret_cast<const float4*>(T2 + (size_t)row * 64 + kc + q * 4);
      }
      int k0 = q * 4;
      Xh[k0 + 0][i] = vh.x; Xh[k0 + 1][i] = vh.y; Xh[k0 + 2][i] = vh.z; Xh[k0 + 3][i] = vh.w;
      Xt1[k0 + 0][i] = v1.x; Xt1[k0 + 1][i] = v1.y; Xt1[k0 + 2][i] = v1.z; Xt1[k0 + 3][i] = v1.w;
      Xt2[k0 + 0][i] = v2.x; Xt2[k0 + 1][i] = v2.y; Xt2[k0 + 2][i] = v2.z; Xt2[k0 + 3][i] = v2.w;
    }
    {
      int kk = t >> 4, dq = (t & 15) * 4;
      float4 w0 = *reinterpret_cast<const float4*>(W2 + (size_t)(kc + kk) * 64 + dq);
      float4 w1 = *reinterpret_cast<const float4*>(W2 + 4096 + (size_t)(kc + kk) * 64 + dq);
      float4 w2 = *reinterpret_cast<const float4*>(W2 + 8192 + (size_t)(kc + kk) * 64 + dq);
      float4 wa = make_float4(w0.x - w2.x, w0.y - w2.y, w0.z - w2.z, w0.w - w2.w);
      float4 wc = make_float4(2.f * w2.x, 2.f * w2.y, 2.f * w2.z, 2.f * w2.w);
      *reinterpret_cast<float4*>(&Wa[kk][dq]) = wa;
      *reinterpret_cast<float4*>(&Wb[kk][dq]) = w1;
      *reinterpret_cast<float4*>(&Wc[kk][dq]) = wc;
    }
    __syncthreads();
#pragma unroll
    for (int kk = 0; kk < 16; ++kk) {
      float4 ha = *reinterpret_cast<const float4*>(&Xh[kk][ng * 8]);
      float4 hb = *reinterpret_cast<const float4*>(&Xh[kk][ng * 8 + 4]);
      float4 p1a = *reinterpret_cast<const float4*>(&Xt1[kk][ng * 8]);
      float4 p1b = *reinterpret_cast<const float4*>(&Xt1[kk][ng * 8 + 4]);
      float4 p2a = *reinterpret_cast<const float4*>(&Xt2[kk][ng * 8]);
      float4 p2b = *reinterpret_cast<const float4*>(&Xt2[kk][ng * 8 + 4]);
      float4 wa = *reinterpret_cast<const float4*>(&Wa[kk][d4]);
      float4 wb = *reinterpret_cast<const float4*>(&Wb[kk][d4]);
      float4 wc = *reinterpret_cast<const float4*>(&Wc[kk][d4]);
      float hr[8] = {ha.x, ha.y, ha.z, ha.w, hb.x, hb.y, hb.z, hb.w};
      float r1[8] = {p1a.x, p1a.y, p1a.z, p1a.w, p1b.x, p1b.y, p1b.z, p1b.w};
      float r2[8] = {p2a.x, p2a.y, p2a.z, p2a.w, p2b.x, p2b.y, p2b.z, p2b.w};
      float war[4] = {wa.x, wa.y, wa.z, wa.w};
      float wbr[4] = {wb.x, wb.y, wb.z, wb.w};
      float wcr[4] = {wc.x, wc.y, wc.z, wc.w};
#pragma unroll
      for (int j = 0; j < 8; ++j)
#pragma unroll
        for (int c = 0; c < 4; ++c)
          acc[j][c] += hr[j] * war[c] + r1[j] * wbr[c] + r2[j] * wcr[c];
    }
    __syncthreads();
  }
  // epilogue: relu + bias into LDS tile (aliased over Xs, safe after barrier)
  float4 bv = *reinterpret_cast<const float4*>(b2v + d4);
#pragma unroll
  for (int j = 0; j < 8; ++j) {
    int r = ng * 8 + j;
    float4 o;
    o.x = fmaxf(acc[j][0] + bv.x, 0.f);
    o.y = fmaxf(acc[j][1] + bv.y, 0.f);
    o.z = fmaxf(acc[j][2] + bv.z, 0.f);
    o.w = fmaxf(acc[j][3] + bv.w, 0.f);
    *reinterpret_cast<float4*>(&ht[r][d4]) = o;
  }
  __syncthreads();
  // segmented pool: batch sorted -> run-length reduce 32 rows per quarter-block
  int rg = t >> 6;
  int d = t & 63;
  int base = rg * 32;
  int cur = -2;
  float s = 0.f;
  for (int i2 = 0; i2 < 32; ++i2) {
    int g = gb[base + i2];  // wave-uniform
    if (g != cur) {
      if (cur >= 0) atomAddF(&pooled[cur * 64 + d], s);
      s = 0.f;
      cur = g;
    }
    if (g >= 0) s += ht[base + i2][d];
  }
  if (cur >= 0) atomAddF(&pooled[cur * 64 + d], s);
}

// Final: out[g] = dot(pooled[g]/max(cnt,1), Wfc) + bfc
__global__ void k_out(const float* __restrict__ pooled, const int* __restrict__ gcnt,
                      const float* __restrict__ Wfc, const float* __restrict__ bfc,
                      float* __restrict__ out) {
  int g = blockIdx.x, t = threadIdx.x;  // 64 threads
  float v = pooled[g * 64 + t] * Wfc[t];
  int c = gcnt[g];
  v /= (float)(c > 0 ? c : 1);
  for (int off = 32; off > 0; off >>= 1) v += __shfl_down(v, off, 64);
  if (t == 0) out[g] = v + bfc[0];
}

// ---------------------------------------------------------------------------
extern "C" void kernel_launch(void* const* d_in, const int* in_sizes, int n_in,
                              void* d_out, int out_size, void* d_ws, size_t ws_size,
                              hipStream_t stream) {
  const float* x   = (const float*)d_in[0];
  const void*  ei  = d_in[1];
  const void*  bat = d_in[2];
  const float* W1  = (const float*)d_in[3];
  const float* b1v = (const float*)d_in[4];
  const float* W2  = (const float*)d_in[5];
  const float* b2v = (const float*)d_in[6];
  const float* Wfc = (const float*)d_in[7];
  const float* bfc = (const float*)d_in[8];
  float* out = (float*)d_out;

  char* w = (char*)d_ws;
  size_t o = 0;
  auto take = [&](size_t bytes) -> void* {
    void* p = w + o;
    o = (o + bytes + 255) & ~(size_t)255;
    return p;
  };
  int*      flag   = (int*)take(256);
  // ---- zero region start
  int*      gcnt   = (int*)take((size_t)NG * 4);
  float*    pooled = (float*)take((size_t)NG * 64 * 4);
  int*      sCnt   = (int*)take((size_t)(NBK + 2) * 4);
  int*      dCnt   = (int*)take((size_t)(NBK + 2) * 4);
  // ---- zero region end
  char*     zend   = w + o;
  int*      sBase  = (int*)take((size_t)(NBK + 2) * 4);
  int*      dBase  = (int*)take((size_t)(NBK + 2) * 4);
  int*      sCur   = (int*)take((size_t)(NBK + 2) * 4);
  int*      dCur   = (int*)take((size_t)(NBK + 2) * 4);
  int*      b32    = (int*)take((size_t)NN * 4);
  float*    dinv   = (float*)take((size_t)NN * 4);
  int*      rowptr = (int*)take((size_t)(NN + 2) * 4);
  int*      srclist= (int*)take((size_t)NE * 4);   // reused as adj after k_deg
  unsigned* elist  = (unsigned*)take((size_t)NE * 4);
  float*    f0     = (float*)take((size_t)NN * 64 * 4);
  float*    f1     = (float*)take((size_t)NN * 64 * 4);
  float*    f2     = (float*)take((size_t)NN * 64 * 4);
  float*    f3     = (float*)take((size_t)NN * 64 * 4);
  float*    f4     = (float*)take((size_t)NN * 64 * 4);
  int*      adj    = srclist;  // alias: srclist dead after k_deg
  (void)in_sizes; (void)n_in; (void)out_size; (void)ws_size;

  hipMemsetAsync(gcnt, 0, (size_t)(zend - (char*)gcnt), stream);

  k_detect<<<1, 64, 0, stream>>>((const int*)ei, flag);
  k_repack_batch<<<(NN + 255) / 256, 256, 0, stream>>>(bat, flag, b32, gcnt);
  k_hist<<<256, 256, 0, stream>>>(ei, flag, sCnt, dCnt);
  k_scan<<<1, 1024, 0, stream>>>(sCnt, dCnt, sBase, dBase, sCur, dCur);
  k_scatter<<<256, 256, 0, stream>>>(ei, flag, sCur, dCur, srclist, elist);
  k_deg<<<NBK, 256, 0, stream>>>(sBase, srclist, dinv);
  k_csr<<<NBK, 256, 0, stream>>>(dBase, elist, rowptr, adj);

  const int gemm_grid = (NN + 127) / 128;  // 782
  const int prop_grid = (NN + 3) / 4;      // 25000

  // Layer 1: V0 -> f4, U1s -> f0, U2s -> f1
  k_gemm_x<<<gemm_grid, 256, 0, stream>>>(x, W1, dinv, f4, f0, f1);
  k_prop2<<<prop_grid, 256, 0, stream>>>(rowptr, adj, f0, f1, dinv, f2, f3); // P->f2, Qs->f3
  k_prop1<<<prop_grid, 256, 0, stream>>>(rowptr, adj, f3, dinv, f1, nullptr); // R->f1
  k_h1<<<(NN * 16 + 255) / 256, 256, 0, stream>>>(f4, f2, f1, b1v, dinv, f3, f0); // h1->f3, h1s->f0
  // Layer 2:
  k_prop1<<<prop_grid, 256, 0, stream>>>(rowptr, adj, f0, dinv, f2, f1);  // T1->f2, T1s->f1
  k_prop1<<<prop_grid, 256, 0, stream>>>(rowptr, adj, f1, dinv, f4, nullptr); // T2->f4
  k_gemm_h2_pool<<<gemm_grid, 256, 0, stream>>>(f3, f2, f4, W2, b2v, b32, pooled);
  k_out<<<NG, 64, 0, stream>>>(pooled, gcnt, Wfc, bfc, out);
}

// Round 4
// 861.578 us; speedup vs baseline: 8.5245x; 1.2034x over previous
//
#include <hip/hip_runtime.h>
#include <hip/hip_fp16.h>
#include <cstdint>
#include <cstddef>

// Problem constants (fixed by the reference)
static constexpr int NN = 100000;   // nodes
static constexpr int NE = 3200000;  // edges
static constexpr int NG = 256;      // graphs
static constexpr int NBK = (NN + 127) / 128;  // dst/src buckets of 128 nodes = 782
static constexpr int EPB = NE / 256;          // edges per hist/scatter block = 12500

__device__ __forceinline__ void atomAddF(float* p, float v) {
  unsafeAtomicAdd(p, v);  // native global_atomic_add_f32 on gfx950
}

__device__ __forceinline__ float h2f(__half h) { return __half2float(h); }

// pack 4 floats -> 4 fp16 (8-byte store; callers guarantee 8B alignment)
__device__ __forceinline__ void st_half4(__half* p, float4 v) {
  ushort4 u;
  u.x = __half_as_ushort(__float2half_rn(v.x));
  u.y = __half_as_ushort(__float2half_rn(v.y));
  u.z = __half_as_ushort(__float2half_rn(v.z));
  u.w = __half_as_ushort(__float2half_rn(v.w));
  *reinterpret_cast<ushort4*>(p) = u;
}

// ---------------------------------------------------------------------------
// dtype hedge: reference says int64, harness doc says int32. Detect at runtime.
__global__ void k_detect(const int* __restrict__ ei, int* __restrict__ flag) {
  if (threadIdx.x == 0 && blockIdx.x == 0) {
    int nz = 0;
    for (int i = 0; i < 64; ++i) nz += (ei[2 * i + 1] != 0) ? 1 : 0;
    *flag = (nz == 0) ? 1 : 0;  // 1 => int64 layout
  }
}

__device__ __forceinline__ int ld_idx(const void* raw, int f, int i) {
  return f ? (int)((const long long*)raw)[i] : ((const int*)raw)[i];
}

// batch repack + graph counts (batch is sorted -> per-block run aggregation)
__global__ __launch_bounds__(256) void k_repack_batch(const void* __restrict__ raw,
                                                      const int* __restrict__ flag,
                                                      int* __restrict__ b32,
                                                      int* __restrict__ gcnt) {
  __shared__ int cnt[256];
  int t = threadIdx.x;
  cnt[t] = 0;
  int blk0 = blockIdx.x * 256;
  int f = *flag;
  int g0 = ld_idx(raw, f, blk0);  // batch sorted, ids < 256 -> g-g0 in [0,255]
  __syncthreads();
  int i = blk0 + t;
  if (i < NN) {
    int g = ld_idx(raw, f, i);
    b32[i] = g;
    atomicAdd(&cnt[g - g0], 1);
  }
  __syncthreads();
  if (cnt[t] > 0) atomicAdd(&gcnt[g0 + t], cnt[t]);
}

// ---------------------------------------------------------------------------
// Pass 1: per-block LDS histograms of src-buckets and dst-buckets.
// Also persists per-block hists so k_scatter can skip its own first pass.
__global__ __launch_bounds__(256) void k_hist(const void* __restrict__ raw,
                                              const int* __restrict__ flag,
                                              int* __restrict__ sCnt,
                                              int* __restrict__ dCnt,
                                              int* __restrict__ hsBlk,
                                              int* __restrict__ hdBlk) {
  __shared__ int hs[NBK], hd[NBK];
  int t = threadIdx.x;
  for (int i = t; i < NBK; i += 256) { hs[i] = 0; hd[i] = 0; }
  __syncthreads();
  int f = *flag;
  int e0 = blockIdx.x * EPB;
  for (int e = e0 + t; e < e0 + EPB; e += 256) {
    int s = ld_idx(raw, f, e);
    int d = ld_idx(raw, f, NE + e);
    atomicAdd(&hs[s >> 7], 1);
    atomicAdd(&hd[d >> 7], 1);
  }
  __syncthreads();
  size_t hb = (size_t)blockIdx.x * NBK;
  for (int i = t; i < NBK; i += 256) {
    int a = hs[i], b = hd[i];
    hsBlk[hb + i] = a;
    hdBlk[hb + i] = b;
    if (a) atomicAdd(&sCnt[i], a);
    if (b) atomicAdd(&dCnt[i], b);
  }
}

// Exclusive scan of both bucket-count arrays (782 <= 1024, one block).
__global__ __launch_bounds__(1024) void k_scan(const int* __restrict__ sCnt,
                                               const int* __restrict__ dCnt,
                                               int* __restrict__ sBase,
                                               int* __restrict__ dBase,
                                               int* __restrict__ sCur,
                                               int* __restrict__ dCur) {
  __shared__ int sh1[1024], sh2[1024];
  int t = threadIdx.x;
  int v1 = (t < NBK) ? sCnt[t] : 0;
  int v2 = (t < NBK) ? dCnt[t] : 0;
  sh1[t] = v1; sh2[t] = v2;
  __syncthreads();
  for (int off = 1; off < 1024; off <<= 1) {
    int a1 = (t >= off) ? sh1[t - off] : 0;
    int a2 = (t >= off) ? sh2[t - off] : 0;
    __syncthreads();
    sh1[t] += a1; sh2[t] += a2;
    __syncthreads();
  }
  if (t <= NBK) {
    int b1 = sh1[t] - v1, b2 = sh2[t] - v2;  // exclusive
    sBase[t] = b1; dBase[t] = b2;
    if (t < NBK) { sCur[t] = b1; dCur[t] = b2; }
  }
}

// Pass 2: chunk-reserve per (block,bucket) using saved per-block hists,
// scatter src ids (by src bucket) and packed (src | dst_local<<17) records.
__global__ __launch_bounds__(256) void k_scatter(const void* __restrict__ raw,
                                                 const int* __restrict__ flag,
                                                 const int* __restrict__ hsBlk,
                                                 const int* __restrict__ hdBlk,
                                                 int* __restrict__ sCur,
                                                 int* __restrict__ dCur,
                                                 int* __restrict__ srclist,
                                                 unsigned* __restrict__ elist) {
  __shared__ int hs[NBK], hd[NBK], cbS[NBK], cbD[NBK];
  int t = threadIdx.x;
  size_t hb = (size_t)blockIdx.x * NBK;
  for (int i = t; i < NBK; i += 256) {
    int c1 = hsBlk[hb + i];
    cbS[i] = c1 ? atomicAdd(&sCur[i], c1) : 0;
    int c2 = hdBlk[hb + i];
    cbD[i] = c2 ? atomicAdd(&dCur[i], c2) : 0;
    hs[i] = 0; hd[i] = 0;
  }
  __syncthreads();
  int f = *flag;
  int e0 = blockIdx.x * EPB;
  for (int e = e0 + t; e < e0 + EPB; e += 256) {
    int s = ld_idx(raw, f, e);
    int d = ld_idx(raw, f, NE + e);
    int bs = s >> 7, bd = d >> 7;
    int ls = atomicAdd(&hs[bs], 1);
    int ld2 = atomicAdd(&hd[bd], 1);
    srclist[cbS[bs] + ls] = s;
    elist[cbD[bd] + ld2] = (unsigned)s | ((unsigned)(d & 127) << 17);
  }
}

// Out-degree per node from src-bucket-sorted list -> dinv.
__global__ __launch_bounds__(256) void k_deg(const int* __restrict__ sBase,
                                             const int* __restrict__ srclist,
                                             float* __restrict__ dinv) {
  __shared__ int cnt[128];
  int t = threadIdx.x;
  if (t < 128) cnt[t] = 0;
  __syncthreads();
  int b = blockIdx.x;
  int e0 = sBase[b], e1 = sBase[b + 1];
  for (int i = e0 + t; i < e1; i += 256) atomicAdd(&cnt[srclist[i] & 127], 1);
  __syncthreads();
  if (t < 128) {
    int node = b * 128 + t;
    if (node < NN) {
      int c = cnt[t];
      dinv[node] = (c > 0) ? rsqrtf((float)c) : 0.f;
    }
  }
}

// Per-bucket counting sort: dst-bucketed elist -> true CSR (rowptr + adj).
__global__ __launch_bounds__(256) void k_csr(const int* __restrict__ dBase,
                                             const unsigned* __restrict__ elist,
                                             int* __restrict__ rowptr,
                                             int* __restrict__ adj) {
  __shared__ int cnt[128], sc[128], off[128], fill[128];
  int t = threadIdx.x;
  if (t < 128) { cnt[t] = 0; fill[t] = 0; }
  __syncthreads();
  int b = blockIdx.x;
  int e0 = dBase[b], e1 = dBase[b + 1];
  for (int i = e0 + t; i < e1; i += 256) atomicAdd(&cnt[elist[i] >> 17], 1);
  __syncthreads();
  if (t < 128) sc[t] = cnt[t];
  __syncthreads();
  for (int o = 1; o < 128; o <<= 1) {
    int a = (t < 128 && t >= o) ? sc[t - o] : 0;
    __syncthreads();
    if (t < 128) sc[t] += a;
    __syncthreads();
  }
  if (t < 128) {
    off[t] = sc[t] - cnt[t];  // exclusive
    int node = b * 128 + t;
    if (node < NN) rowptr[node] = e0 + off[t];
  }
  if (b == NBK - 1 && t == 0) rowptr[NN] = e1;
  __syncthreads();
  for (int i = e0 + t; i < e1; i += 256) {
    unsigned w2 = elist[i];
    int l = (int)(w2 >> 17);
    int pos = atomicAdd(&fill[l], 1);
    adj[e0 + off[l] + pos] = (int)(w2 & 0x1FFFFu);
  }
}

// ---------------------------------------------------------------------------
// Propagation (single fp16 input): wave per node, lane = dim, f32 accumulate.
// o_p = -dinv .* sum_{e->i} vin[src];  o_s = fp16(dinv .* o_p)  (may be null)
__global__ __launch_bounds__(256) void k_prop1(const int* __restrict__ rp,
                                               const int* __restrict__ adj,
                                               const __half* __restrict__ vin,
                                               const float* __restrict__ dinv,
                                               float* __restrict__ o_p,
                                               __half* __restrict__ o_s) {
  int node = blockIdx.x * 4 + (threadIdx.x >> 6);
  int d = threadIdx.x & 63;
  if (node >= NN) return;
  int p0 = rp[node], p1 = rp[node + 1];
  float a0 = 0.f, a1 = 0.f, a2 = 0.f, a3 = 0.f;
  int p = p0;
  int pA = (p0 + 3) & ~3;
  if (pA > p1) pA = p1;
  for (; p < pA; ++p) a0 += h2f(vin[(size_t)adj[p] * 64 + d]);
  for (; p + 8 <= p1; p += 8) {
    int4 e0 = *reinterpret_cast<const int4*>(adj + p);      // uniform 16B loads
    int4 e1 = *reinterpret_cast<const int4*>(adj + p + 4);
    a0 += h2f(vin[(size_t)e0.x * 64 + d]);
    a1 += h2f(vin[(size_t)e0.y * 64 + d]);
    a2 += h2f(vin[(size_t)e0.z * 64 + d]);
    a3 += h2f(vin[(size_t)e0.w * 64 + d]);
    a0 += h2f(vin[(size_t)e1.x * 64 + d]);
    a1 += h2f(vin[(size_t)e1.y * 64 + d]);
    a2 += h2f(vin[(size_t)e1.z * 64 + d]);
    a3 += h2f(vin[(size_t)e1.w * 64 + d]);
  }
  if (p + 4 <= p1) {
    int4 e = *reinterpret_cast<const int4*>(adj + p);
    a0 += h2f(vin[(size_t)e.x * 64 + d]);
    a1 += h2f(vin[(size_t)e.y * 64 + d]);
    a2 += h2f(vin[(size_t)e.z * 64 + d]);
    a3 += h2f(vin[(size_t)e.w * 64 + d]);
    p += 4;
  }
  for (; p < p1; ++p) a1 += h2f(vin[(size_t)adj[p] * 64 + d]);
  float s = (a0 + a1) + (a2 + a3);
  float dv = dinv[node];
  float pl = -dv * s;
  if (o_p) o_p[(size_t)node * 64 + d] = pl;
  if (o_s) o_s[(size_t)node * 64 + d] = __float2half_rn(dv * pl);
}

// Propagation (two fp16 inputs, shared adjacency): A -> f32 plain, B -> fp16 scaled.
__global__ __launch_bounds__(256) void k_prop2(const int* __restrict__ rp,
                                               const int* __restrict__ adj,
                                               const __half* __restrict__ vinA,
                                               const __half* __restrict__ vinB,
                                               const float* __restrict__ dinv,
                                               float* __restrict__ oA_p,
                                               __half* __restrict__ oB_s) {
  int node = blockIdx.x * 4 + (threadIdx.x >> 6);
  int d = threadIdx.x & 63;
  if (node >= NN) return;
  int p0 = rp[node], p1 = rp[node + 1];
  float a0 = 0.f, a1 = 0.f, a2 = 0.f, a3 = 0.f;
  float b0 = 0.f, b1 = 0.f, b2 = 0.f, b3 = 0.f;
  int p = p0;
  int pA = (p0 + 3) & ~3;
  if (pA > p1) pA = p1;
  for (; p < pA; ++p) {
    size_t r = (size_t)adj[p] * 64 + d;
    a0 += h2f(vinA[r]); b0 += h2f(vinB[r]);
  }
  for (; p + 8 <= p1; p += 8) {
    int4 e0 = *reinterpret_cast<const int4*>(adj + p);
    int4 e1 = *reinterpret_cast<const int4*>(adj + p + 4);
    size_t r0 = (size_t)e0.x * 64 + d, r1 = (size_t)e0.y * 64 + d;
    size_t r2 = (size_t)e0.z * 64 + d, r3 = (size_t)e0.w * 64 + d;
    size_t r4 = (size_t)e1.x * 64 + d, r5 = (size_t)e1.y * 64 + d;
    size_t r6 = (size_t)e1.z * 64 + d, r7 = (size_t)e1.w * 64 + d;
    a0 += h2f(vinA[r0]); b0 += h2f(vinB[r0]);
    a1 += h2f(vinA[r1]); b1 += h2f(vinB[r1]);
    a2 += h2f(vinA[r2]); b2 += h2f(vinB[r2]);
    a3 += h2f(vinA[r3]); b3 += h2f(vinB[r3]);
    a0 += h2f(vinA[r4]); b0 += h2f(vinB[r4]);
    a1 += h2f(vinA[r5]); b1 += h2f(vinB[r5]);
    a2 += h2f(vinA[r6]); b2 += h2f(vinB[r6]);
    a3 += h2f(vinA[r7]); b3 += h2f(vinB[r7]);
  }
  if (p + 4 <= p1) {
    int4 e = *reinterpret_cast<const int4*>(adj + p);
    size_t r0 = (size_t)e.x * 64 + d, r1 = (size_t)e.y * 64 + d;
    size_t r2 = (size_t)e.z * 64 + d, r3 = (size_t)e.w * 64 + d;
    a0 += h2f(vinA[r0]); b0 += h2f(vinB[r0]);
    a1 += h2f(vinA[r1]); b1 += h2f(vinB[r1]);
    a2 += h2f(vinA[r2]); b2 += h2f(vinB[r2]);
    a3 += h2f(vinA[r3]); b3 += h2f(vinB[r3]);
    p += 4;
  }
  for (; p < p1; ++p) {
    size_t r = (size_t)adj[p] * 64 + d;
    a1 += h2f(vinA[r]); b1 += h2f(vinB[r]);
  }
  float sa = (a0 + a1) + (a2 + a3);
  float sb = (b0 + b1) + (b2 + b3);
  float dv = dinv[node];
  oA_p[(size_t)node * 64 + d] = -dv * sa;
  oB_s[(size_t)node * 64 + d] = __float2half_rn(-dv * dv * sb);
}

// ---------------------------------------------------------------------------
// GEMM X: V0 = x@(W1[0]-W1[2]) (f32), hU1 = fp16(dinv.*(x@W1[1])),
//         hU2 = fp16(dinv.*(x@W1[2])).
__global__ __launch_bounds__(256) void k_gemm_x(const float* __restrict__ x,
                                                const float* __restrict__ W1,
                                                const float* __restrict__ dinv,
                                                float* __restrict__ V0,
                                                __half* __restrict__ hU1,
                                                __half* __restrict__ hU2) {
  __shared__ __align__(16) float Xs[16][132];
  __shared__ __align__(16) float WsA[16][64];  // W0 - W2
  __shared__ __align__(16) float WsB[16][64];  // W1
  __shared__ __align__(16) float WsC[16][64];  // W2
  const int t = threadIdx.x;
  const int d4 = (t & 15) * 4;
  const int ng = t >> 4;
  const int n0 = blockIdx.x * 128;
  float acc0[8][4], acc1[8][4], acc2[8][4];
#pragma unroll
  for (int j = 0; j < 8; ++j)
#pragma unroll
    for (int c = 0; c < 4; ++c) { acc0[j][c] = 0.f; acc1[j][c] = 0.f; acc2[j][c] = 0.f; }

  for (int kc = 0; kc < 128; kc += 16) {
#pragma unroll
    for (int u = 0; u < 2; ++u) {
      int lin = t * 2 + u;
      int i = lin >> 2, q = lin & 3;
      int row = n0 + i;
      float4 v = make_float4(0.f, 0.f, 0.f, 0.f);
      if (row < NN) v = *reinterpret_cast<const float4*>(x + (size_t)row * 128 + kc + q * 4);
      int k0 = q * 4;
      Xs[k0 + 0][i] = v.x; Xs[k0 + 1][i] = v.y; Xs[k0 + 2][i] = v.z; Xs[k0 + 3][i] = v.w;
    }
    {
      int kk = t >> 4, dq = (t & 15) * 4;
      float4 w0 = *reinterpret_cast<const float4*>(W1 + (size_t)(kc + kk) * 64 + dq);
      float4 w1 = *reinterpret_cast<const float4*>(W1 + (size_t)(8192 + (kc + kk) * 64) + dq);
      float4 w2 = *reinterpret_cast<const float4*>(W1 + (size_t)(16384 + (kc + kk) * 64) + dq);
      *reinterpret_cast<float4*>(&WsA[kk][dq]) =
          make_float4(w0.x - w2.x, w0.y - w2.y, w0.z - w2.z, w0.w - w2.w);
      *reinterpret_cast<float4*>(&WsB[kk][dq]) = w1;
      *reinterpret_cast<float4*>(&WsC[kk][dq]) = w2;
    }
    __syncthreads();
#pragma unroll
    for (int kk = 0; kk < 16; ++kk) {
      float4 xa = *reinterpret_cast<const float4*>(&Xs[kk][ng * 8]);
      float4 xb = *reinterpret_cast<const float4*>(&Xs[kk][ng * 8 + 4]);
      float4 wa = *reinterpret_cast<const float4*>(&WsA[kk][d4]);
      float4 wb = *reinterpret_cast<const float4*>(&WsB[kk][d4]);
      float4 wc = *reinterpret_cast<const float4*>(&WsC[kk][d4]);
      float xr[8] = {xa.x, xa.y, xa.z, xa.w, xb.x, xb.y, xb.z, xb.w};
      float war[4] = {wa.x, wa.y, wa.z, wa.w};
      float wbr[4] = {wb.x, wb.y, wb.z, wb.w};
      float wcr[4] = {wc.x, wc.y, wc.z, wc.w};
#pragma unroll
      for (int j = 0; j < 8; ++j)
#pragma unroll
        for (int c = 0; c < 4; ++c) {
          acc0[j][c] += xr[j] * war[c];
          acc1[j][c] += xr[j] * wbr[c];
          acc2[j][c] += xr[j] * wcr[c];
        }
    }
    __syncthreads();
  }
#pragma unroll
  for (int j = 0; j < 8; ++j) {
    int row = n0 + ng * 8 + j;
    if (row < NN) {
      float dv = dinv[row];
      *reinterpret_cast<float4*>(V0 + (size_t)row * 64 + d4) =
          make_float4(acc0[j][0], acc0[j][1], acc0[j][2], acc0[j][3]);
      st_half4(hU1 + (size_t)row * 64 + d4,
               make_float4(dv * acc1[j][0], dv * acc1[j][1], dv * acc1[j][2], dv * acc1[j][3]));
      st_half4(hU2 + (size_t)row * 64 + d4,
               make_float4(dv * acc2[j][0], dv * acc2[j][1], dv * acc2[j][2], dv * acc2[j][3]));
    }
  }
}

// h1 = relu(V0 + P + 2R + b1) (f32); h1s = fp16(dinv .* h1)
__global__ __launch_bounds__(256) void k_h1(const float* __restrict__ V0,
                                            const float* __restrict__ P,
                                            const float* __restrict__ R,
                                            const float* __restrict__ b1v,
                                            const float* __restrict__ dinv,
                                            float* __restrict__ h1,
                                            __half* __restrict__ h1s) {
  int idx = blockIdx.x * 256 + threadIdx.x;
  if (idx >= NN * 16) return;
  int row = idx >> 4, c = (idx & 15) * 4;
  float dv = dinv[row];
  float4 v0 = *reinterpret_cast<const float4*>(V0 + (size_t)row * 64 + c);
  float4 p = *reinterpret_cast<const float4*>(P + (size_t)row * 64 + c);
  float4 r = *reinterpret_cast<const float4*>(R + (size_t)row * 64 + c);
  float4 b = *reinterpret_cast<const float4*>(b1v + c);
  float4 h;
  h.x = fmaxf(v0.x + p.x + 2.f * r.x + b.x, 0.f);
  h.y = fmaxf(v0.y + p.y + 2.f * r.y + b.y, 0.f);
  h.z = fmaxf(v0.z + p.z + 2.f * r.z + b.z, 0.f);
  h.w = fmaxf(v0.w + p.w + 2.f * r.w + b.w, 0.f);
  *reinterpret_cast<float4*>(h1 + (size_t)row * 64 + c) = h;
  st_half4(h1s + (size_t)row * 64 + c,
           make_float4(dv * h.x, dv * h.y, dv * h.z, dv * h.w));
}

// GEMM C: h2 = relu(h1@(W2[0]-W2[2]) + T1@W2[1] + T2@(2*W2[2]) + b2),
// fused segmented mean-pool numerator (batch sorted) into pooled[] atomics.
__global__ __launch_bounds__(256) void k_gemm_h2_pool(const float* __restrict__ h1,
                                                      const float* __restrict__ T1,
                                                      const float* __restrict__ T2,
                                                      const float* __restrict__ W2,
                                                      const float* __restrict__ b2v,
                                                      const int* __restrict__ b32,
                                                      float* __restrict__ pooled) {
  __shared__ __align__(16) float smem[9408];  // 3*16*132 + 3*16*64
  __shared__ int gb[128];
  float (*Xh)[132]  = reinterpret_cast<float (*)[132]>(smem);
  float (*Xt1)[132] = reinterpret_cast<float (*)[132]>(smem + 2112);
  float (*Xt2)[132] = reinterpret_cast<float (*)[132]>(smem + 4224);
  float (*Wa)[64]   = reinterpret_cast<float (*)[64]>(smem + 6336);
  float (*Wb)[64]   = reinterpret_cast<float (*)[64]>(smem + 7360);
  float (*Wc)[64]   = reinterpret_cast<float (*)[64]>(smem + 8384);
  float (*ht)[68]   = reinterpret_cast<float (*)[68]>(smem);  // aliases Xs after K-loop

  const int t = threadIdx.x;
  const int d4 = (t & 15) * 4;
  const int ng = t >> 4;
  const int n0 = blockIdx.x * 128;
  if (t < 128) gb[t] = (n0 + t < NN) ? b32[n0 + t] : -1;

  float acc[8][4];
#pragma unroll
  for (int j = 0; j < 8; ++j)
#pragma unroll
    for (int c = 0; c < 4; ++c) acc[j][c] = 0.f;

  for (int kc = 0; kc < 64; kc += 16) {
#pragma unroll
    for (int u = 0; u < 2; ++u) {
      int lin = t * 2 + u;
      int i = lin >> 2, q = lin & 3;
      int row = n0 + i;
      float4 vh = make_float4(0.f, 0.f, 0.f, 0.f), v1 = vh, v2 = vh;
      if (row < NN) {
        vh = *reinterpret_cast<const float4*>(h1 + (size_t)row * 64 + kc + q * 4);
        v1 = *reinterpret_cast<const float4*>(T1 + (size_t)row * 64 + kc + q * 4);
        v2 = *reinterpret_cast<const float4*>(T2 + (size_t)row * 64 + kc + q * 4);
      }
      int k0 = q * 4;
      Xh[k0 + 0][i] = vh.x; Xh[k0 + 1][i] = vh.y; Xh[k0 + 2][i] = vh.z; Xh[k0 + 3][i] = vh.w;
      Xt1[k0 + 0][i] = v1.x; Xt1[k0 + 1][i] = v1.y; Xt1[k0 + 2][i] = v1.z; Xt1[k0 + 3][i] = v1.w;
      Xt2[k0 + 0][i] = v2.x; Xt2[k0 + 1][i] = v2.y; Xt2[k0 + 2][i] = v2.z; Xt2[k0 + 3][i] = v2.w;
    }
    {
      int kk = t >> 4, dq = (t & 15) * 4;
      float4 w0 = *reinterpret_cast<const float4*>(W2 + (size_t)(kc + kk) * 64 + dq);
      float4 w1 = *reinterpret_cast<const float4*>(W2 + 4096 + (size_t)(kc + kk) * 64 + dq);
      float4 w2 = *reinterpret_cast<const float4*>(W2 + 8192 + (size_t)(kc + kk) * 64 + dq);
      float4 wa = make_float4(w0.x - w2.x, w0.y - w2.y, w0.z - w2.z, w0.w - w2.w);
      float4 wc = make_float4(2.f * w2.x, 2.f * w2.y, 2.f * w2.z, 2.f * w2.w);
      *reinterpret_cast<float4*>(&Wa[kk][dq]) = wa;
      *reinterpret_cast<float4*>(&Wb[kk][dq]) = w1;
      *reinterpret_cast<float4*>(&Wc[kk][dq]) = wc;
    }
    __syncthreads();
#pragma unroll
    for (int kk = 0; kk < 16; ++kk) {
      float4 ha = *reinterpret_cast<const float4*>(&Xh[kk][ng * 8]);
      float4 hb = *reinterpret_cast<const float4*>(&Xh[kk][ng * 8 + 4]);
      float4 p1a = *reinterpret_cast<const float4*>(&Xt1[kk][ng * 8]);
      float4 p1b = *reinterpret_cast<const float4*>(&Xt1[kk][ng * 8 + 4]);
      float4 p2a = *reinterpret_cast<const float4*>(&Xt2[kk][ng * 8]);
      float4 p2b = *reinterpret_cast<const float4*>(&Xt2[kk][ng * 8 + 4]);
      float4 wa = *reinterpret_cast<const float4*>(&Wa[kk][d4]);
      float4 wb = *reinterpret_cast<const float4*>(&Wb[kk][d4]);
      float4 wc = *reinterpret_cast<const float4*>(&Wc[kk][d4]);
      float hr[8] = {ha.x, ha.y, ha.z, ha.w, hb.x, hb.y, hb.z, hb.w};
      float r1[8] = {p1a.x, p1a.y, p1a.z, p1a.w, p1b.x, p1b.y, p1b.z, p1b.w};
      float r2[8] = {p2a.x, p2a.y, p2a.z, p2a.w, p2b.x, p2b.y, p2b.z, p2b.w};
      float war[4] = {wa.x, wa.y, wa.z, wa.w};
      float wbr[4] = {wb.x, wb.y, wb.z, wb.w};
      float wcr[4] = {wc.x, wc.y, wc.z, wc.w};
#pragma unroll
      for (int j = 0; j < 8; ++j)
#pragma unroll
        for (int c = 0; c < 4; ++c)
          acc[j][c] += hr[j] * war[c] + r1[j] * wbr[c] + r2[j] * wcr[c];
    }
    __syncthreads();
  }
  // epilogue: relu + bias into LDS tile (aliased over Xs, safe after barrier)
  float4 bv = *reinterpret_cast<const float4*>(b2v + d4);
#pragma unroll
  for (int j = 0; j < 8; ++j) {
    int r = ng * 8 + j;
    float4 o;
    o.x = fmaxf(acc[j][0] + bv.x, 0.f);
    o.y = fmaxf(acc[j][1] + bv.y, 0.f);
    o.z = fmaxf(acc[j][2] + bv.z, 0.f);
    o.w = fmaxf(acc[j][3] + bv.w, 0.f);
    *reinterpret_cast<float4*>(&ht[r][d4]) = o;
  }
  __syncthreads();
  // segmented pool: batch sorted -> run-length reduce 32 rows per quarter-block
  int rg = t >> 6;
  int d = t & 63;
  int base = rg * 32;
  int cur = -2;
  float s = 0.f;
  for (int i2 = 0; i2 < 32; ++i2) {
    int g = gb[base + i2];  // wave-uniform
    if (g != cur) {
      if (cur >= 0) atomAddF(&pooled[cur * 64 + d], s);
      s = 0.f;
      cur = g;
    }
    if (g >= 0) s += ht[base + i2][d];
  }
  if (cur >= 0) atomAddF(&pooled[cur * 64 + d], s);
}

// Final: out[g] = dot(pooled[g]/max(cnt,1), Wfc) + bfc
__global__ void k_out(const float* __restrict__ pooled, const int* __restrict__ gcnt,
                      const float* __restrict__ Wfc, const float* __restrict__ bfc,
                      float* __restrict__ out) {
  int g = blockIdx.x, t = threadIdx.x;  // 64 threads
  float v = pooled[g * 64 + t] * Wfc[t];
  int c = gcnt[g];
  v /= (float)(c > 0 ? c : 1);
  for (int off = 32; off > 0; off >>= 1) v += __shfl_down(v, off, 64);
  if (t == 0) out[g] = v + bfc[0];
}

// ---------------------------------------------------------------------------
extern "C" void kernel_launch(void* const* d_in, const int* in_sizes, int n_in,
                              void* d_out, int out_size, void* d_ws, size_t ws_size,
                              hipStream_t stream) {
  const float* x   = (const float*)d_in[0];
  const void*  ei  = d_in[1];
  const void*  bat = d_in[2];
  const float* W1  = (const float*)d_in[3];
  const float* b1v = (const float*)d_in[4];
  const float* W2  = (const float*)d_in[5];
  const float* b2v = (const float*)d_in[6];
  const float* Wfc = (const float*)d_in[7];
  const float* bfc = (const float*)d_in[8];
  float* out = (float*)d_out;

  char* w = (char*)d_ws;
  size_t o = 0;
  auto take = [&](size_t bytes) -> void* {
    void* p = w + o;
    o = (o + bytes + 255) & ~(size_t)255;
    return p;
  };
  int*      flag   = (int*)take(256);
  // ---- zero region start
  int*      gcnt   = (int*)take((size_t)NG * 4);
  float*    pooled = (float*)take((size_t)NG * 64 * 4);
  int*      sCnt   = (int*)take((size_t)(NBK + 2) * 4);
  int*      dCnt   = (int*)take((size_t)(NBK + 2) * 4);
  // ---- zero region end
  char*     zend   = w + o;
  int*      sBase  = (int*)take((size_t)(NBK + 2) * 4);
  int*      dBase  = (int*)take((size_t)(NBK + 2) * 4);
  int*      sCur   = (int*)take((size_t)(NBK + 2) * 4);
  int*      dCur   = (int*)take((size_t)(NBK + 2) * 4);
  int*      b32    = (int*)take((size_t)NN * 4);
  float*    dinv   = (float*)take((size_t)NN * 4);
  int*      rowptr = (int*)take((size_t)(NN + 2) * 4);
  int*      hsBlk  = (int*)take((size_t)256 * NBK * 4);
  int*      hdBlk  = (int*)take((size_t)256 * NBK * 4);
  int*      srclist= (int*)take((size_t)NE * 4);   // reused as adj after k_deg
  unsigned* elist  = (unsigned*)take((size_t)NE * 4);
  float*    f1     = (float*)take((size_t)NN * 64 * 4);
  float*    f2     = (float*)take((size_t)NN * 64 * 4);
  float*    f3     = (float*)take((size_t)NN * 64 * 4);
  float*    f4     = (float*)take((size_t)NN * 64 * 4);
  __half*   g0     = (__half*)take((size_t)NN * 64 * 2);
  __half*   g1     = (__half*)take((size_t)NN * 64 * 2);
  __half*   g2     = (__half*)take((size_t)NN * 64 * 2);
  int*      adj    = srclist;  // alias: srclist dead after k_deg
  (void)in_sizes; (void)n_in; (void)out_size; (void)ws_size;

  hipMemsetAsync(gcnt, 0, (size_t)(zend - (char*)gcnt), stream);

  k_detect<<<1, 64, 0, stream>>>((const int*)ei, flag);
  k_repack_batch<<<(NN + 255) / 256, 256, 0, stream>>>(bat, flag, b32, gcnt);
  k_hist<<<256, 256, 0, stream>>>(ei, flag, sCnt, dCnt, hsBlk, hdBlk);
  k_scan<<<1, 1024, 0, stream>>>(sCnt, dCnt, sBase, dBase, sCur, dCur);
  k_scatter<<<256, 256, 0, stream>>>(ei, flag, hsBlk, hdBlk, sCur, dCur, srclist, elist);
  k_deg<<<NBK, 256, 0, stream>>>(sBase, srclist, dinv);
  k_csr<<<NBK, 256, 0, stream>>>(dBase, elist, rowptr, adj);

  const int gemm_grid = (NN + 127) / 128;  // 782
  const int prop_grid = (NN + 3) / 4;      // 25000

  // Layer 1: V0 -> f4, hU1s -> g0, hU2s -> g1
  k_gemm_x<<<gemm_grid, 256, 0, stream>>>(x, W1, dinv, f4, g0, g1);
  k_prop2<<<prop_grid, 256, 0, stream>>>(rowptr, adj, g0, g1, dinv, f2, g2); // P->f2, hQs->g2
  k_prop1<<<prop_grid, 256, 0, stream>>>(rowptr, adj, g2, dinv, f1, nullptr); // R->f1
  k_h1<<<(NN * 16 + 255) / 256, 256, 0, stream>>>(f4, f2, f1, b1v, dinv, f3, g0); // h1->f3, h1s->g0
  // Layer 2:
  k_prop1<<<prop_grid, 256, 0, stream>>>(rowptr, adj, g0, dinv, f2, g1);  // T1->f2, hT1s->g1
  k_prop1<<<prop_grid, 256, 0, stream>>>(rowptr, adj, g1, dinv, f4, nullptr); // T2->f4
  k_gemm_h2_pool<<<gemm_grid, 256, 0, stream>>>(f3, f2, f4, W2, b2v, b32, pooled);
  k_out<<<NG, 64, 0, stream>>>(pooled, gcnt, Wfc, bfc, out);
}

// Round 5
// 680.510 us; speedup vs baseline: 10.7927x; 1.2661x over previous
//
#include <hip/hip_runtime.h>
#include <hip/hip_fp16.h>
#include <cstdint>
#include <cstddef>

// Problem constants (fixed by the reference)
static constexpr int NN = 100000;   // nodes
static constexpr int NE = 3200000;  // edges
static constexpr int NG = 256;      // graphs
static constexpr int NBK = (NN + 127) / 128;  // dst/src buckets of 128 nodes = 782
static constexpr int EPB = NE / 256;          // edges per hist/scatter block = 12500

typedef _Float16 h8 __attribute__((ext_vector_type(8)));
typedef float f4v __attribute__((ext_vector_type(4)));

__device__ __forceinline__ void atomAddF(float* p, float v) {
  unsafeAtomicAdd(p, v);  // native global_atomic_add_f32 on gfx950
}

__device__ __forceinline__ float h2f(__half h) { return __half2float(h); }

__device__ __forceinline__ unsigned pk2(float a, float b) {
  unsigned lo = __half_as_ushort(__float2half_rn(a));
  unsigned hi = __half_as_ushort(__float2half_rn(b));
  return lo | (hi << 16);
}

// ---------------------------------------------------------------------------
// dtype hedge: reference says int64, harness doc says int32. Detect at runtime.
__global__ void k_detect(const int* __restrict__ ei, int* __restrict__ flag) {
  if (threadIdx.x == 0 && blockIdx.x == 0) {
    int nz = 0;
    for (int i = 0; i < 64; ++i) nz += (ei[2 * i + 1] != 0) ? 1 : 0;
    *flag = (nz == 0) ? 1 : 0;  // 1 => int64 layout
  }
}

__device__ __forceinline__ int ld_idx(const void* raw, int f, int i) {
  return f ? (int)((const long long*)raw)[i] : ((const int*)raw)[i];
}

// batch repack + graph counts (batch is sorted -> per-block run aggregation)
__global__ __launch_bounds__(256) void k_repack_batch(const void* __restrict__ raw,
                                                      const int* __restrict__ flag,
                                                      int* __restrict__ b32,
                                                      int* __restrict__ gcnt) {
  __shared__ int cnt[256];
  int t = threadIdx.x;
  cnt[t] = 0;
  int blk0 = blockIdx.x * 256;
  int f = *flag;
  int g0 = ld_idx(raw, f, blk0);
  __syncthreads();
  int i = blk0 + t;
  if (i < NN) {
    int g = ld_idx(raw, f, i);
    b32[i] = g;
    atomicAdd(&cnt[g - g0], 1);
  }
  __syncthreads();
  if (cnt[t] > 0) atomicAdd(&gcnt[g0 + t], cnt[t]);
}

// ---------------------------------------------------------------------------
// Pass 1: per-block LDS histograms of src-buckets and dst-buckets (persisted).
__global__ __launch_bounds__(256) void k_hist(const void* __restrict__ raw,
                                              const int* __restrict__ flag,
                                              int* __restrict__ sCnt,
                                              int* __restrict__ dCnt,
                                              int* __restrict__ hsBlk,
                                              int* __restrict__ hdBlk) {
  __shared__ int hs[NBK], hd[NBK];
  int t = threadIdx.x;
  for (int i = t; i < NBK; i += 256) { hs[i] = 0; hd[i] = 0; }
  __syncthreads();
  int f = *flag;
  int e0 = blockIdx.x * EPB;
  for (int e = e0 + t; e < e0 + EPB; e += 256) {
    int s = ld_idx(raw, f, e);
    int d = ld_idx(raw, f, NE + e);
    atomicAdd(&hs[s >> 7], 1);
    atomicAdd(&hd[d >> 7], 1);
  }
  __syncthreads();
  size_t hb = (size_t)blockIdx.x * NBK;
  for (int i = t; i < NBK; i += 256) {
    int a = hs[i], b = hd[i];
    hsBlk[hb + i] = a;
    hdBlk[hb + i] = b;
    if (a) atomicAdd(&sCnt[i], a);
    if (b) atomicAdd(&dCnt[i], b);
  }
}

// Exclusive scan of both bucket-count arrays (782 <= 1024, one block).
__global__ __launch_bounds__(1024) void k_scan(const int* __restrict__ sCnt,
                                               const int* __restrict__ dCnt,
                                               int* __restrict__ sBase,
                                               int* __restrict__ dBase,
                                               int* __restrict__ sCur,
                                               int* __restrict__ dCur) {
  __shared__ int sh1[1024], sh2[1024];
  int t = threadIdx.x;
  int v1 = (t < NBK) ? sCnt[t] : 0;
  int v2 = (t < NBK) ? dCnt[t] : 0;
  sh1[t] = v1; sh2[t] = v2;
  __syncthreads();
  for (int off = 1; off < 1024; off <<= 1) {
    int a1 = (t >= off) ? sh1[t - off] : 0;
    int a2 = (t >= off) ? sh2[t - off] : 0;
    __syncthreads();
    sh1[t] += a1; sh2[t] += a2;
    __syncthreads();
  }
  if (t <= NBK) {
    int b1 = sh1[t] - v1, b2 = sh2[t] - v2;  // exclusive
    sBase[t] = b1; dBase[t] = b2;
    if (t < NBK) { sCur[t] = b1; dCur[t] = b2; }
  }
}

// Pass 2: chunk-reserve per (block,bucket) using saved per-block hists,
// scatter src ids (by src bucket) and packed (src | dst_local<<17) records.
__global__ __launch_bounds__(256) void k_scatter(const void* __restrict__ raw,
                                                 const int* __restrict__ flag,
                                                 const int* __restrict__ hsBlk,
                                                 const int* __restrict__ hdBlk,
                                                 int* __restrict__ sCur,
                                                 int* __restrict__ dCur,
                                                 int* __restrict__ srclist,
                                                 unsigned* __restrict__ elist) {
  __shared__ int hs[NBK], hd[NBK], cbS[NBK], cbD[NBK];
  int t = threadIdx.x;
  size_t hb = (size_t)blockIdx.x * NBK;
  for (int i = t; i < NBK; i += 256) {
    int c1 = hsBlk[hb + i];
    cbS[i] = c1 ? atomicAdd(&sCur[i], c1) : 0;
    int c2 = hdBlk[hb + i];
    cbD[i] = c2 ? atomicAdd(&dCur[i], c2) : 0;
    hs[i] = 0; hd[i] = 0;
  }
  __syncthreads();
  int f = *flag;
  int e0 = blockIdx.x * EPB;
  for (int e = e0 + t; e < e0 + EPB; e += 256) {
    int s = ld_idx(raw, f, e);
    int d = ld_idx(raw, f, NE + e);
    int bs = s >> 7, bd = d >> 7;
    int ls = atomicAdd(&hs[bs], 1);
    int ld2 = atomicAdd(&hd[bd], 1);
    srclist[cbS[bs] + ls] = s;
    elist[cbD[bd] + ld2] = (unsigned)s | ((unsigned)(d & 127) << 17);
  }
}

// Out-degree per node from src-bucket-sorted list -> dinv.
__global__ __launch_bounds__(256) void k_deg(const int* __restrict__ sBase,
                                             const int* __restrict__ srclist,
                                             float* __restrict__ dinv) {
  __shared__ int cnt[128];
  int t = threadIdx.x;
  if (t < 128) cnt[t] = 0;
  __syncthreads();
  int b = blockIdx.x;
  int e0 = sBase[b], e1 = sBase[b + 1];
  for (int i = e0 + t; i < e1; i += 256) atomicAdd(&cnt[srclist[i] & 127], 1);
  __syncthreads();
  if (t < 128) {
    int node = b * 128 + t;
    if (node < NN) {
      int c = cnt[t];
      dinv[node] = (c > 0) ? rsqrtf((float)c) : 0.f;
    }
  }
}

// Per-bucket counting sort: dst-bucketed elist -> true CSR (rowptr + adj).
__global__ __launch_bounds__(256) void k_csr(const int* __restrict__ dBase,
                                             const unsigned* __restrict__ elist,
                                             int* __restrict__ rowptr,
                                             int* __restrict__ adj) {
  __shared__ int cnt[128], sc[128], off[128], fill[128];
  int t = threadIdx.x;
  if (t < 128) { cnt[t] = 0; fill[t] = 0; }
  __syncthreads();
  int b = blockIdx.x;
  int e0 = dBase[b], e1 = dBase[b + 1];
  for (int i = e0 + t; i < e1; i += 256) atomicAdd(&cnt[elist[i] >> 17], 1);
  __syncthreads();
  if (t < 128) sc[t] = cnt[t];
  __syncthreads();
  for (int o = 1; o < 128; o <<= 1) {
    int a = (t < 128 && t >= o) ? sc[t - o] : 0;
    __syncthreads();
    if (t < 128) sc[t] += a;
    __syncthreads();
  }
  if (t < 128) {
    off[t] = sc[t] - cnt[t];  // exclusive
    int node = b * 128 + t;
    if (node < NN) rowptr[node] = e0 + off[t];
  }
  if (b == NBK - 1 && t == 0) rowptr[NN] = e1;
  __syncthreads();
  for (int i = e0 + t; i < e1; i += 256) {
    unsigned w2 = elist[i];
    int l = (int)(w2 >> 17);
    int pos = atomicAdd(&fill[l], 1);
    adj[e0 + off[l] + pos] = (int)(w2 & 0x1FFFFu);
  }
}

// ---------------------------------------------------------------------------
// Weight prep: BtX[192][128] fp16 (x-GEMM, transposed, W0-W2 folded),
//              BtH[64][192] fp16 (h2-GEMM over [h1|T1|T2], transforms folded).
__global__ __launch_bounds__(256) void k_prepW(const float* __restrict__ W1,
                                               const float* __restrict__ W2,
                                               __half* __restrict__ BtX,
                                               __half* __restrict__ BtH) {
  int t = blockIdx.x * 256 + threadIdx.x;
  if (t < 192 * 128) {
    int n = t >> 7, k = t & 127;
    float v;
    if (n < 64)       v = W1[k * 64 + n] - W1[16384 + k * 64 + n];
    else if (n < 128) v = W1[8192 + k * 64 + (n - 64)];
    else              v = W1[16384 + k * 64 + (n - 128)];
    BtX[n * 128 + k] = __float2half_rn(v);
  } else if (t < 192 * 128 + 64 * 192) {
    int u = t - 192 * 128;
    int n = u / 192, k = u % 192;
    int s = k >> 6, kk = k & 63;
    float v = (s == 0) ? (W2[kk * 64 + n] - W2[8192 + kk * 64 + n])
            : (s == 1) ? W2[4096 + kk * 64 + n]
                       : 2.f * W2[8192 + kk * 64 + n];
    BtH[n * 192 + k] = __float2half_rn(v);
  }
}

// ---------------------------------------------------------------------------
// MFMA GEMM X: [128 nodes] x [K=128] x [N=192].
// Outputs: gV0 fp16 (cols 0..63), p01 packed half2 {dinv*U1, dinv*U2} (cols 64..191).
static constexpr int AW = 136;  // LDS row stride (halves), pad 8 -> balanced banks
__global__ __launch_bounds__(256) void k_gemm_x(const float* __restrict__ x,
                                                const __half* __restrict__ BtX,
                                                const float* __restrict__ dinv,
                                                __half* __restrict__ gV0,
                                                unsigned* __restrict__ p01) {
  __shared__ __align__(16) _Float16 As[128 * AW];
  const int t = threadIdx.x;
  const int n0 = blockIdx.x * 128;
  {  // stage A tile as fp16: thread t -> row t>>1, half-row t&1
    int i = t >> 1, q = t & 1;
    int row = n0 + i;
    _Float16* dst = As + i * AW + q * 64;
    if (row < NN) {
      const float* src = x + (size_t)row * 128 + q * 64;
#pragma unroll
      for (int c = 0; c < 64; c += 4) {
        float4 v = *reinterpret_cast<const float4*>(src + c);
        ushort4 u;
        u.x = __half_as_ushort(__float2half_rn(v.x));
        u.y = __half_as_ushort(__float2half_rn(v.y));
        u.z = __half_as_ushort(__float2half_rn(v.z));
        u.w = __half_as_ushort(__float2half_rn(v.w));
        *reinterpret_cast<ushort4*>(dst + c) = u;
      }
    } else {
#pragma unroll
      for (int c = 0; c < 64; c += 4)
        *reinterpret_cast<ushort4*>(dst + c) = make_ushort4(0, 0, 0, 0);
    }
  }
  __syncthreads();
  const int w = t >> 6, lane = t & 63;
  const int quad = lane >> 4, l = lane & 15;
  f4v acc[2][12];
#pragma unroll
  for (int mt = 0; mt < 2; ++mt)
#pragma unroll
    for (int nt = 0; nt < 12; ++nt) acc[mt][nt] = (f4v){0.f, 0.f, 0.f, 0.f};

#pragma unroll
  for (int ks = 0; ks < 4; ++ks) {
    int k0 = ks * 32 + quad * 8;
    h8 a0 = *reinterpret_cast<const h8*>(As + (w * 32 + l) * AW + k0);
    h8 a1 = *reinterpret_cast<const h8*>(As + (w * 32 + 16 + l) * AW + k0);
#pragma unroll
    for (int nt = 0; nt < 12; ++nt) {
      h8 b = *reinterpret_cast<const h8*>(BtX + (size_t)(nt * 16 + l) * 128 + k0);
      acc[0][nt] = __builtin_amdgcn_mfma_f32_16x16x32_f16(a0, b, acc[0][nt], 0, 0, 0);
      acc[1][nt] = __builtin_amdgcn_mfma_f32_16x16x32_f16(a1, b, acc[1][nt], 0, 0, 0);
    }
  }
  // epilogue: D row = quad*4 + r, col = l  (within each 16x16 tile)
#pragma unroll
  for (int mt = 0; mt < 2; ++mt) {
#pragma unroll
    for (int r = 0; r < 4; ++r) {
      int row = n0 + w * 32 + mt * 16 + quad * 4 + r;
      if (row < NN) {
        float dv = dinv[row];
#pragma unroll
        for (int nt2 = 0; nt2 < 4; ++nt2) {
          gV0[(size_t)row * 64 + nt2 * 16 + l] = __float2half_rn(acc[mt][nt2][r]);
          p01[(size_t)row * 64 + nt2 * 16 + l] =
              pk2(dv * acc[mt][4 + nt2][r], dv * acc[mt][8 + nt2][r]);
        }
      }
    }
  }
}

// ---------------------------------------------------------------------------
// Propagation (packed half2 input): one 4B gather feeds both sums.
// oA = fp16(-dinv*sum(lo)), oB = fp16(-dinv^2*sum(hi))
__global__ __launch_bounds__(256) void k_prop2p(const int* __restrict__ rp,
                                                const int* __restrict__ adj,
                                                const unsigned* __restrict__ vp,
                                                const float* __restrict__ dinv,
                                                __half* __restrict__ oA,
                                                __half* __restrict__ oB) {
  int node = blockIdx.x * 4 + (threadIdx.x >> 6);
  int d = threadIdx.x & 63;
  if (node >= NN) return;
  int p0 = rp[node], p1 = rp[node + 1];
  float a0 = 0.f, a1 = 0.f, a2 = 0.f, a3 = 0.f;
  float b0 = 0.f, b1 = 0.f, b2 = 0.f, b3 = 0.f;
  union { unsigned u; __half2 h; } cv;
  int p = p0;
  int pA = (p0 + 3) & ~3;
  if (pA > p1) pA = p1;
  for (; p < pA; ++p) {
    cv.u = vp[(size_t)adj[p] * 64 + d];
    float2 f = __half22float2(cv.h);
    a0 += f.x; b0 += f.y;
  }
  for (; p + 8 <= p1; p += 8) {
    int4 e0 = *reinterpret_cast<const int4*>(adj + p);
    int4 e1 = *reinterpret_cast<const int4*>(adj + p + 4);
    unsigned u0 = vp[(size_t)e0.x * 64 + d], u1 = vp[(size_t)e0.y * 64 + d];
    unsigned u2 = vp[(size_t)e0.z * 64 + d], u3 = vp[(size_t)e0.w * 64 + d];
    unsigned u4 = vp[(size_t)e1.x * 64 + d], u5 = vp[(size_t)e1.y * 64 + d];
    unsigned u6 = vp[(size_t)e1.z * 64 + d], u7 = vp[(size_t)e1.w * 64 + d];
    cv.u = u0; { float2 f = __half22float2(cv.h); a0 += f.x; b0 += f.y; }
    cv.u = u1; { float2 f = __half22float2(cv.h); a1 += f.x; b1 += f.y; }
    cv.u = u2; { float2 f = __half22float2(cv.h); a2 += f.x; b2 += f.y; }
    cv.u = u3; { float2 f = __half22float2(cv.h); a3 += f.x; b3 += f.y; }
    cv.u = u4; { float2 f = __half22float2(cv.h); a0 += f.x; b0 += f.y; }
    cv.u = u5; { float2 f = __half22float2(cv.h); a1 += f.x; b1 += f.y; }
    cv.u = u6; { float2 f = __half22float2(cv.h); a2 += f.x; b2 += f.y; }
    cv.u = u7; { float2 f = __half22float2(cv.h); a3 += f.x; b3 += f.y; }
  }
  if (p + 4 <= p1) {
    int4 e = *reinterpret_cast<const int4*>(adj + p);
    unsigned u0 = vp[(size_t)e.x * 64 + d], u1 = vp[(size_t)e.y * 64 + d];
    unsigned u2 = vp[(size_t)e.z * 64 + d], u3 = vp[(size_t)e.w * 64 + d];
    cv.u = u0; { float2 f = __half22float2(cv.h); a0 += f.x; b0 += f.y; }
    cv.u = u1; { float2 f = __half22float2(cv.h); a1 += f.x; b1 += f.y; }
    cv.u = u2; { float2 f = __half22float2(cv.h); a2 += f.x; b2 += f.y; }
    cv.u = u3; { float2 f = __half22float2(cv.h); a3 += f.x; b3 += f.y; }
    p += 4;
  }
  for (; p < p1; ++p) {
    cv.u = vp[(size_t)adj[p] * 64 + d];
    float2 f = __half22float2(cv.h);
    a1 += f.x; b1 += f.y;
  }
  float sa = (a0 + a1) + (a2 + a3);
  float sb = (b0 + b1) + (b2 + b3);
  float dv = dinv[node];
  oA[(size_t)node * 64 + d] = __float2half_rn(-dv * sa);
  oB[(size_t)node * 64 + d] = __float2half_rn(-dv * dv * sb);
}

// Propagation (fp16 single input): o_p = fp16(-dinv*sum), o_s = fp16(dinv*o_p) (opt)
__global__ __launch_bounds__(256) void k_prop1(const int* __restrict__ rp,
                                               const int* __restrict__ adj,
                                               const __half* __restrict__ vin,
                                               const float* __restrict__ dinv,
                                               __half* __restrict__ o_p,
                                               __half* __restrict__ o_s) {
  int node = blockIdx.x * 4 + (threadIdx.x >> 6);
  int d = threadIdx.x & 63;
  if (node >= NN) return;
  int p0 = rp[node], p1 = rp[node + 1];
  float a0 = 0.f, a1 = 0.f, a2 = 0.f, a3 = 0.f;
  int p = p0;
  int pA = (p0 + 3) & ~3;
  if (pA > p1) pA = p1;
  for (; p < pA; ++p) a0 += h2f(vin[(size_t)adj[p] * 64 + d]);
  for (; p + 8 <= p1; p += 8) {
    int4 e0 = *reinterpret_cast<const int4*>(adj + p);
    int4 e1 = *reinterpret_cast<const int4*>(adj + p + 4);
    a0 += h2f(vin[(size_t)e0.x * 64 + d]);
    a1 += h2f(vin[(size_t)e0.y * 64 + d]);
    a2 += h2f(vin[(size_t)e0.z * 64 + d]);
    a3 += h2f(vin[(size_t)e0.w * 64 + d]);
    a0 += h2f(vin[(size_t)e1.x * 64 + d]);
    a1 += h2f(vin[(size_t)e1.y * 64 + d]);
    a2 += h2f(vin[(size_t)e1.z * 64 + d]);
    a3 += h2f(vin[(size_t)e1.w * 64 + d]);
  }
  if (p + 4 <= p1) {
    int4 e = *reinterpret_cast<const int4*>(adj + p);
    a0 += h2f(vin[(size_t)e.x * 64 + d]);
    a1 += h2f(vin[(size_t)e.y * 64 + d]);
    a2 += h2f(vin[(size_t)e.z * 64 + d]);
    a3 += h2f(vin[(size_t)e.w * 64 + d]);
    p += 4;
  }
  for (; p < p1; ++p) a1 += h2f(vin[(size_t)adj[p] * 64 + d]);
  float s = (a0 + a1) + (a2 + a3);
  float dv = dinv[node];
  float pl = -dv * s;
  o_p[(size_t)node * 64 + d] = __float2half_rn(pl);
  if (o_s) o_s[(size_t)node * 64 + d] = __float2half_rn(dv * pl);
}

// Propagation fused with h1: R = -dinv*sum(gQs); h1 = relu(V0 + P + 2R + b1);
// gH1 = fp16(h1), gH1s = fp16(dinv*h1)
__global__ __launch_bounds__(256) void k_prop_h1(const int* __restrict__ rp,
                                                 const int* __restrict__ adj,
                                                 const __half* __restrict__ vin,
                                                 const float* __restrict__ dinv,
                                                 const __half* __restrict__ gV0,
                                                 const __half* __restrict__ gP,
                                                 const float* __restrict__ b1v,
                                                 __half* __restrict__ gH1,
                                                 __half* __restrict__ gH1s) {
  int node = blockIdx.x * 4 + (threadIdx.x >> 6);
  int d = threadIdx.x & 63;
  if (node >= NN) return;
  int p0 = rp[node], p1 = rp[node + 1];
  float a0 = 0.f, a1 = 0.f, a2 = 0.f, a3 = 0.f;
  int p = p0;
  int pA = (p0 + 3) & ~3;
  if (pA > p1) pA = p1;
  for (; p < pA; ++p) a0 += h2f(vin[(size_t)adj[p] * 64 + d]);
  for (; p + 8 <= p1; p += 8) {
    int4 e0 = *reinterpret_cast<const int4*>(adj + p);
    int4 e1 = *reinterpret_cast<const int4*>(adj + p + 4);
    a0 += h2f(vin[(size_t)e0.x * 64 + d]);
    a1 += h2f(vin[(size_t)e0.y * 64 + d]);
    a2 += h2f(vin[(size_t)e0.z * 64 + d]);
    a3 += h2f(vin[(size_t)e0.w * 64 + d]);
    a0 += h2f(vin[(size_t)e1.x * 64 + d]);
    a1 += h2f(vin[(size_t)e1.y * 64 + d]);
    a2 += h2f(vin[(size_t)e1.z * 64 + d]);
    a3 += h2f(vin[(size_t)e1.w * 64 + d]);
  }
  if (p + 4 <= p1) {
    int4 e = *reinterpret_cast<const int4*>(adj + p);
    a0 += h2f(vin[(size_t)e.x * 64 + d]);
    a1 += h2f(vin[(size_t)e.y * 64 + d]);
    a2 += h2f(vin[(size_t)e.z * 64 + d]);
    a3 += h2f(vin[(size_t)e.w * 64 + d]);
    p += 4;
  }
  for (; p < p1; ++p) a1 += h2f(vin[(size_t)adj[p] * 64 + d]);
  float s = (a0 + a1) + (a2 + a3);
  float dv = dinv[node];
  float R = -dv * s;
  size_t idx = (size_t)node * 64 + d;
  float h = h2f(gV0[idx]) + h2f(gP[idx]) + 2.f * R + b1v[d];
  h = fmaxf(h, 0.f);
  gH1[idx] = __float2half_rn(h);
  gH1s[idx] = __float2half_rn(dv * h);
}

// ---------------------------------------------------------------------------
// MFMA GEMM H2 + pool: A = [h1|T1|T2] (128 x 192 fp16), B = BtH (192 x 64),
// relu+bias into LDS, then segmented mean-pool numerator into pooled[].
static constexpr int HW = 200;  // LDS row stride (halves)
__global__ __launch_bounds__(256) void k_gemm_h2_pool(const __half* __restrict__ gH1,
                                                      const __half* __restrict__ gT1,
                                                      const __half* __restrict__ gT2,
                                                      const __half* __restrict__ BtH,
                                                      const float* __restrict__ b2v,
                                                      const int* __restrict__ b32,
                                                      float* __restrict__ pooled) {
  __shared__ __align__(16) char smem[128 * HW * 2];  // 51.2 KB
  __shared__ int gb[128];
  _Float16* As = reinterpret_cast<_Float16*>(smem);
  const int t = threadIdx.x;
  const int n0 = blockIdx.x * 128;
  if (t < 128) gb[t] = (n0 + t < NN) ? b32[n0 + t] : -1;
  // stage A: 128 rows x 24 chunks of 8 halves; chunk seg: 0-7 h1, 8-15 T1, 16-23 T2
  for (int c = t; c < 128 * 24; c += 256) {
    int row = c / 24, seg = c % 24;
    int tb = seg >> 3, off = (seg & 7) * 8;
    int rowg = n0 + row;
    h8 v = (h8){0, 0, 0, 0, 0, 0, 0, 0};
    if (rowg < NN) {
      const __half* src = (tb == 0 ? gH1 : tb == 1 ? gT1 : gT2) + (size_t)rowg * 64 + off;
      v = *reinterpret_cast<const h8*>(src);
    }
    *reinterpret_cast<h8*>(As + row * HW + seg * 8) = v;
  }
  __syncthreads();
  const int w = t >> 6, lane = t & 63;
  const int quad = lane >> 4, l = lane & 15;
  f4v acc[2][4];
#pragma unroll
  for (int mt = 0; mt < 2; ++mt)
#pragma unroll
    for (int nt = 0; nt < 4; ++nt) acc[mt][nt] = (f4v){0.f, 0.f, 0.f, 0.f};
#pragma unroll
  for (int ks = 0; ks < 6; ++ks) {
    int k0 = ks * 32 + quad * 8;
    h8 a0 = *reinterpret_cast<const h8*>(As + (w * 32 + l) * HW + k0);
    h8 a1 = *reinterpret_cast<const h8*>(As + (w * 32 + 16 + l) * HW + k0);
#pragma unroll
    for (int nt = 0; nt < 4; ++nt) {
      h8 b = *reinterpret_cast<const h8*>(BtH + (size_t)(nt * 16 + l) * 192 + k0);
      acc[0][nt] = __builtin_amdgcn_mfma_f32_16x16x32_f16(a0, b, acc[0][nt], 0, 0, 0);
      acc[1][nt] = __builtin_amdgcn_mfma_f32_16x16x32_f16(a1, b, acc[1][nt], 0, 0, 0);
    }
  }
  __syncthreads();  // done reading As; reuse LDS as ht[128][68] f32
  float (*ht)[68] = reinterpret_cast<float (*)[68]>(smem);
#pragma unroll
  for (int mt = 0; mt < 2; ++mt)
#pragma unroll
    for (int r = 0; r < 4; ++r) {
      int rl = w * 32 + mt * 16 + quad * 4 + r;
#pragma unroll
      for (int nt = 0; nt < 4; ++nt) {
        int col = nt * 16 + l;
        ht[rl][col] = fmaxf(acc[mt][nt][r] + b2v[col], 0.f);
      }
    }
  __syncthreads();
  // segmented pool: batch sorted -> run-length reduce 32 rows per wave
  int rg = t >> 6;
  int d = t & 63;
  int base = rg * 32;
  int cur = -2;
  float s = 0.f;
  for (int i2 = 0; i2 < 32; ++i2) {
    int g = gb[base + i2];  // wave-uniform
    if (g != cur) {
      if (cur >= 0) atomAddF(&pooled[cur * 64 + d], s);
      s = 0.f;
      cur = g;
    }
    if (g >= 0) s += ht[base + i2][d];
  }
  if (cur >= 0) atomAddF(&pooled[cur * 64 + d], s);
}

// Final: out[g] = dot(pooled[g]/max(cnt,1), Wfc) + bfc
__global__ void k_out(const float* __restrict__ pooled, const int* __restrict__ gcnt,
                      const float* __restrict__ Wfc, const float* __restrict__ bfc,
                      float* __restrict__ out) {
  int g = blockIdx.x, t = threadIdx.x;  // 64 threads
  float v = pooled[g * 64 + t] * Wfc[t];
  int c = gcnt[g];
  v /= (float)(c > 0 ? c : 1);
  for (int off = 32; off > 0; off >>= 1) v += __shfl_down(v, off, 64);
  if (t == 0) out[g] = v + bfc[0];
}

// ---------------------------------------------------------------------------
extern "C" void kernel_launch(void* const* d_in, const int* in_sizes, int n_in,
                              void* d_out, int out_size, void* d_ws, size_t ws_size,
                              hipStream_t stream) {
  const float* x   = (const float*)d_in[0];
  const void*  ei  = d_in[1];
  const void*  bat = d_in[2];
  const float* W1  = (const float*)d_in[3];
  const float* b1v = (const float*)d_in[4];
  const float* W2  = (const float*)d_in[5];
  const float* b2v = (const float*)d_in[6];
  const float* Wfc = (const float*)d_in[7];
  const float* bfc = (const float*)d_in[8];
  float* out = (float*)d_out;

  char* w = (char*)d_ws;
  size_t o = 0;
  auto take = [&](size_t bytes) -> void* {
    void* p = w + o;
    o = (o + bytes + 255) & ~(size_t)255;
    return p;
  };
  int*      flag   = (int*)take(256);
  // ---- zero region start
  int*      gcnt   = (int*)take((size_t)NG * 4);
  float*    pooled = (float*)take((size_t)NG * 64 * 4);
  int*      sCnt   = (int*)take((size_t)(NBK + 2) * 4);
  int*      dCnt   = (int*)take((size_t)(NBK + 2) * 4);
  // ---- zero region end
  char*     zend   = w + o;
  int*      sBase  = (int*)take((size_t)(NBK + 2) * 4);
  int*      dBase  = (int*)take((size_t)(NBK + 2) * 4);
  int*      sCur   = (int*)take((size_t)(NBK + 2) * 4);
  int*      dCur   = (int*)take((size_t)(NBK + 2) * 4);
  int*      b32    = (int*)take((size_t)NN * 4);
  float*    dinv   = (float*)take((size_t)NN * 4);
  int*      rowptr = (int*)take((size_t)(NN + 2) * 4);
  int*      hsBlk  = (int*)take((size_t)256 * NBK * 4);
  int*      hdBlk  = (int*)take((size_t)256 * NBK * 4);
  int*      srclist= (int*)take((size_t)NE * 4);   // reused as adj after k_deg
  unsigned* elist  = (unsigned*)take((size_t)NE * 4);
  __half*   BtX    = (__half*)take((size_t)192 * 128 * 2);
  __half*   BtH    = (__half*)take((size_t)64 * 192 * 2);
  __half*   gV0    = (__half*)take((size_t)NN * 64 * 2);
  unsigned* p01    = (unsigned*)take((size_t)NN * 64 * 4);
  __half*   gP     = (__half*)take((size_t)NN * 64 * 2);
  __half*   gQs    = (__half*)take((size_t)NN * 64 * 2);
  __half*   gH1    = (__half*)take((size_t)NN * 64 * 2);
  __half*   gH1s   = (__half*)take((size_t)NN * 64 * 2);
  __half*   gT1    = (__half*)take((size_t)NN * 64 * 2);
  __half*   gT1s   = (__half*)take((size_t)NN * 64 * 2);
  __half*   gT2    = (__half*)take((size_t)NN * 64 * 2);
  int*      adj    = srclist;  // alias: srclist dead after k_deg
  (void)in_sizes; (void)n_in; (void)out_size; (void)ws_size;

  hipMemsetAsync(gcnt, 0, (size_t)(zend - (char*)gcnt), stream);

  k_detect<<<1, 64, 0, stream>>>((const int*)ei, flag);
  k_repack_batch<<<(NN + 255) / 256, 256, 0, stream>>>(bat, flag, b32, gcnt);
  k_prepW<<<(192 * 128 + 64 * 192 + 255) / 256, 256, 0, stream>>>(W1, W2, BtX, BtH);
  k_hist<<<256, 256, 0, stream>>>(ei, flag, sCnt, dCnt, hsBlk, hdBlk);
  k_scan<<<1, 1024, 0, stream>>>(sCnt, dCnt, sBase, dBase, sCur, dCur);
  k_scatter<<<256, 256, 0, stream>>>(ei, flag, hsBlk, hdBlk, sCur, dCur, srclist, elist);
  k_deg<<<NBK, 256, 0, stream>>>(sBase, srclist, dinv);
  k_csr<<<NBK, 256, 0, stream>>>(dBase, elist, rowptr, adj);

  const int gemm_grid = (NN + 127) / 128;  // 782
  const int prop_grid = (NN + 3) / 4;      // 25000

  // Layer 1
  k_gemm_x<<<gemm_grid, 256, 0, stream>>>(x, BtX, dinv, gV0, p01);
  k_prop2p<<<prop_grid, 256, 0, stream>>>(rowptr, adj, p01, dinv, gP, gQs);
  k_prop_h1<<<prop_grid, 256, 0, stream>>>(rowptr, adj, gQs, dinv, gV0, gP, b1v, gH1, gH1s);
  // Layer 2
  k_prop1<<<prop_grid, 256, 0, stream>>>(rowptr, adj, gH1s, dinv, gT1, gT1s);
  k_prop1<<<prop_grid, 256, 0, stream>>>(rowptr, adj, gT1s, dinv, gT2, nullptr);
  k_gemm_h2_pool<<<gemm_grid, 256, 0, stream>>>(gH1, gT1, gT2, BtH, b2v, b32, pooled);
  k_out<<<NG, 64, 0, stream>>>(pooled, gcnt, Wfc, bfc, out);
}